// Round 1
// baseline (423.800 us; speedup 1.0000x reference)
//
#include <hip/hip_runtime.h>
#include <hip/hip_bf16.h>
#include <math.h>

// MAGNN link prediction forward — fp32 compute; feat table stored bf16.
// Tower GEMM1 now runs on MFMA (split-bf16 hi/lo, 3 MFMAs -> ~fp32 accuracy).
#define NN0 20000
#define NN1 20000
#define NTOT 40000
#define FF0 512
#define HIDD 64
#define EEE 200000
#define BBB 8192
#define AVV 128
#define CHH 128

typedef __bf16 bf16x8 __attribute__((ext_vector_type(8)));
typedef __bf16 bf16x4 __attribute__((ext_vector_type(4)));
typedef float f32x4 __attribute__((ext_vector_type(4)));

__device__ __forceinline__ float fast_tanh(float x) {
    float e2 = __expf(2.f * x);
    return 1.f - 2.f / (e2 + 1.f);
}

// ---------------- weight prep: transpose + hi/lo bf16 split + XOR swizzle ----------------
// Output layout per (tower, chunk c of 64 k): 16KB image = hi[4096 bf16] || lo[4096 bf16],
// where byte (n*128 + ((kk*2) ^ ((n&7)<<4))) of each half holds w[c*64+kk][n].
// This is exactly the LDS image the tower kernel copies linearly and reads conflict-free.
__global__ __launch_bounds__(256) void prep_w(const float* __restrict__ pw0,
                                              const float* __restrict__ pw1,
                                              __bf16* __restrict__ wprep)
{
    int tw = blockIdx.x;
    const float* w = tw ? pw1 : pw0;
    for (int idx = threadIdx.x; idx < FF0 * 64; idx += 256) {
        int k = idx >> 6, n = idx & 63;          // w[k][n], row-major [512][64]
        int c = k >> 6, kk = k & 63;
        float v = w[idx];
        __bf16 hi = (__bf16)v;
        __bf16 lo = (__bf16)(v - (float)hi);
        int dstb = n * 128 + ((kk * 2) ^ ((n & 7) << 4));
        __bf16* base = wprep + (long)(tw * 8 + c) * 8192;
        base[dstb >> 1] = hi;
        base[4096 + (dstb >> 1)] = lo;
    }
}

// ---------------- tower: MFMA GEMM1 (512->64) + GELU + VALU GEMM2 (64->64) + residual + LN ---
// 64-row blocks, 4 waves; wave w owns rows [16w,16w+16), full 64 cols (4 col-tiles).
// GEMM1: split-bf16 x (hi/lo) and w (hi/lo from prep); acc += hi*hi + lo*hi + hi*lo.
// LDS phase 1: A[2][64][64] bf16 (16KB, XOR-swizzled) + B[2][64][64] bf16 (16KB).
// LDS phase 2 (aliases phase 1): zs[64][68] f32 + hs[64][68] f32 + w2s[64][64] f32 = 51.2KB.
__global__ __launch_bounds__(256) void tower_kernel(
    const float* __restrict__ x0, const float* __restrict__ x1,
    const __bf16* __restrict__ wprep,
    const float* __restrict__ pb0, const float* __restrict__ pb1,
    const float* __restrict__ w20, const float* __restrict__ w21,
    const float* __restrict__ b20, const float* __restrict__ b21,
    const float* __restrict__ g0, const float* __restrict__ g1,
    const float* __restrict__ be0, const float* __restrict__ be1,
    const int* __restrict__ idxa, const int* __restrict__ idxb,
    __hip_bfloat16* __restrict__ feat)
{
    int tw = blockIdx.y;
    const float* x  = tw ? x1 : x0;
    const float* pb = tw ? pb1 : pb0;
    const float* w2 = tw ? w21 : w20;
    const float* b2 = tw ? b21 : b20;
    const float* g  = tw ? g1 : g0;
    const float* be = tw ? be1 : be0;
    const int* idx  = tw ? idxb : idxa;
    const int nrows = NN0;

    __shared__ __align__(16) char smem[51200];
    char* Ab = smem;                 // bf16 [2][64][64]: hi @0, lo @8192
    char* Bb = smem + 16384;         // bf16 [2][64][64]: hi @0, lo @8192
    float (*zs)[68]  = (float(*)[68])smem;             // phase 2
    float (*hs)[68]  = (float(*)[68])(smem + 17408);
    float (*w2s)[64] = (float(*)[64])(smem + 34816);

    int tid = threadIdx.x;
    int lane = tid & 63, wid = tid >> 6;
    int row0 = blockIdx.x * 64;
    const __bf16* wp = wprep + (long)tw * 8 * 8192;

    int sr = tid >> 4;              // staging row (0..15), +16 per q
    int sk4 = (tid & 15) * 4;       // staging k (float4)

    float4 xv[4];
    bf16x8 wv[4];

    auto issue_loads = [&](int c) {
        int k0 = c * 64;
#pragma unroll
        for (int q = 0; q < 4; q++) {
            int gr = row0 + sr + q * 16;
            xv[q] = (gr < nrows) ? *(const float4*)&x[(long)gr * FF0 + k0 + sk4]
                                 : make_float4(0.f, 0.f, 0.f, 0.f);
        }
        const char* img = (const char*)(wp + (long)c * 8192);
#pragma unroll
        for (int q = 0; q < 4; q++)
            wv[q] = *(const bf16x8*)(img + q * 4096 + tid * 16);
    };

    f32x4 acc[4];
#pragma unroll
    for (int nt = 0; nt < 4; nt++) acc[nt] = (f32x4){0.f, 0.f, 0.f, 0.f};

    int fr = lane & 15, kb = lane >> 4;
    int sw = (fr & 7) << 4;                    // fragment-read swizzle (row&7 == fr&7)

    issue_loads(0);
    for (int c = 0; c < 8; c++) {
        __syncthreads();                       // previous chunk's reads done
        // ---- write staged A (convert + split + swizzle) ----
#pragma unroll
        for (int q = 0; q < 4; q++) {
            int r = sr + q * 16;
            int byt = r * 128 + ((sk4 * 2) ^ ((r & 7) << 4));
            float vv[4] = {xv[q].x, xv[q].y, xv[q].z, xv[q].w};
            bf16x4 hi, lo;
#pragma unroll
            for (int j = 0; j < 4; j++) {
                hi[j] = (__bf16)vv[j];
                lo[j] = (__bf16)(vv[j] - (float)hi[j]);
            }
            *(bf16x4*)(Ab + byt) = hi;
            *(bf16x4*)(Ab + 8192 + byt) = lo;
        }
        // ---- write staged B (already in LDS image order) ----
#pragma unroll
        for (int q = 0; q < 4; q++)
            *(bf16x8*)(Bb + q * 4096 + tid * 16) = wv[q];
        __syncthreads();
        if (c + 1 < 8) issue_loads(c + 1);     // T14: hide HBM latency under MFMA
        // ---- MFMA: 2 k-steps x 4 col-tiles x 3 (hh, lh, hl) ----
#pragma unroll
        for (int ks = 0; ks < 2; ks++) {
            int ko = ks * 64 + kb * 16;
            int ra = (wid * 16 + fr) * 128 + (ko ^ sw);
            bf16x8 ah = *(const bf16x8*)(Ab + ra);
            bf16x8 al = *(const bf16x8*)(Ab + 8192 + ra);
#pragma unroll
            for (int nt = 0; nt < 4; nt++) {
                int rb = (nt * 16 + fr) * 128 + (ko ^ sw);
                bf16x8 bh = *(const bf16x8*)(Bb + rb);
                bf16x8 bl = *(const bf16x8*)(Bb + 8192 + rb);
                acc[nt] = __builtin_amdgcn_mfma_f32_16x16x32_bf16(ah, bh, acc[nt], 0, 0, 0);
                acc[nt] = __builtin_amdgcn_mfma_f32_16x16x32_bf16(al, bh, acc[nt], 0, 0, 0);
                acc[nt] = __builtin_amdgcn_mfma_f32_16x16x32_bf16(ah, bl, acc[nt], 0, 0, 0);
            }
        }
    }
    __syncthreads();                           // MFMA reads done; smem is reusable

    // ---- epilogue 1: z = acc + pb; zs/hs from MFMA C layout (col=lane&15, row=(lane>>4)*4+j)
    int rg = lane >> 4;
#pragma unroll
    for (int nt = 0; nt < 4; nt++) {
        int col = nt * 16 + fr;
        float pbv = pb[col];
#pragma unroll
        for (int j = 0; j < 4; j++) {
            int row = wid * 16 + rg * 4 + j;
            float z = acc[nt][j] + pbv;
            zs[row][col] = z;
            hs[row][col] = 0.5f * z * (1.f + erff(z * 0.70710678118654752f));
        }
    }
    // stage w2 (fp32)
    const float4* w24 = (const float4*)w2;
#pragma unroll
    for (int q = 0; q < 4; q++) {
        int li = tid + q * 256;
        *(float4*)&w2s[li >> 4][(li & 15) * 4] = w24[li];
    }
    __syncthreads();

    // ---- GEMM2 (VALU fp32): y = h@w2 + b2 + z ; each thread 4 rows x 4 cols ----
    int ct = tid & 15, rt = tid >> 4;
    float4 b2v = *(const float4*)&b2[4 * ct];
    float acc2[4][4];
#pragma unroll
    for (int j = 0; j < 4; j++) {
        acc2[j][0] = zs[4 * rt + j][4 * ct]     + b2v.x;
        acc2[j][1] = zs[4 * rt + j][4 * ct + 1] + b2v.y;
        acc2[j][2] = zs[4 * rt + j][4 * ct + 2] + b2v.z;
        acc2[j][3] = zs[4 * rt + j][4 * ct + 3] + b2v.w;
    }
    for (int k = 0; k < 64; k += 4) {
        float4 hv[4];
#pragma unroll
        for (int j = 0; j < 4; j++) hv[j] = *(const float4*)&hs[4 * rt + j][k];
#pragma unroll
        for (int kk = 0; kk < 4; kk++) {
            float4 wvv = *(const float4*)&w2s[k + kk][4 * ct];
#pragma unroll
            for (int j = 0; j < 4; j++) {
                float a = kk == 0 ? hv[j].x : kk == 1 ? hv[j].y : kk == 2 ? hv[j].z : hv[j].w;
                acc2[j][0] = fmaf(a, wvv.x, acc2[j][0]);
                acc2[j][1] = fmaf(a, wvv.y, acc2[j][1]);
                acc2[j][2] = fmaf(a, wvv.z, acc2[j][2]);
                acc2[j][3] = fmaf(a, wvv.w, acc2[j][3]);
            }
        }
    }
    // write y back into zs (each thread owns its cells), then LN
#pragma unroll
    for (int j = 0; j < 4; j++)
        *(float4*)&zs[4 * rt + j][4 * ct] = make_float4(acc2[j][0], acc2[j][1], acc2[j][2], acc2[j][3]);
    __syncthreads();

    // ---- LayerNorm: lane = col, 4 waves x 16 rows ----
    float gc = g[lane], bec = be[lane];
    for (int rr = wid; rr < 64; rr += 4) {
        float y = zs[rr][lane];
        float mu = y;
        for (int off = 32; off; off >>= 1) mu += __shfl_xor(mu, off);
        mu *= (1.f / 64.f);
        float d = y - mu;
        float var = d * d;
        for (int off = 32; off; off >>= 1) var += __shfl_xor(var, off);
        var *= (1.f / 64.f);
        float o = d / sqrtf(var + 1e-5f) * gc + bec;
        int grow = row0 + rr;
        if (grow < nrows) feat[(long)idx[grow] * HIDD + lane] = __float2bfloat16(o);
    }
}

// ---------------- CSR build: hist -> scan -> binA (coarse) -> binB (exact) ----------------
__global__ void hist_kernel(const int* __restrict__ tgt_user, const int* __restrict__ tgt_item,
                            int* __restrict__ cnt)
{
    int combo = blockIdx.y;
    const int* tgt = (combo < 2 ? tgt_user : tgt_item) + (long)(combo & 1) * EEE;
    int i = blockIdx.x * 256 + threadIdx.x;
    if (i < EEE) atomicAdd(&cnt[combo * BBB + tgt[i]], 1);
}

__global__ __launch_bounds__(256) void scan_kernel(const int* __restrict__ cnt, int* __restrict__ offs,
                                                   int* __restrict__ cur32, float* __restrict__ s_acc)
{
    int pth = blockIdx.x;
    if (pth == 0 && threadIdx.x < 4) s_acc[threadIdx.x] = 0.f;
    const int* c = cnt + pth * BBB;
    int* o = offs + pth * (BBB + 1);
    __shared__ int part[256];
    int tid = threadIdx.x;
    int base = tid * 32;
    int local[32];
    int sum = 0;
    for (int j = 0; j < 32; j++) { local[j] = sum; sum += c[base + j]; }
    part[tid] = sum;
    __syncthreads();
    for (int d = 1; d < 256; d <<= 1) {
        int v = (tid >= d) ? part[tid - d] : 0;
        __syncthreads();
        part[tid] += v;
        __syncthreads();
    }
    int pre = (tid == 0) ? 0 : part[tid - 1];
    for (int j = 0; j < 32; j++) {
        int val = pre + local[j];
        o[base + j] = val;
        if (((base + j) & 255) == 0) cur32[pth * 32 + ((base + j) >> 8)] = val;
    }
    if (tid == 255) o[BBB] = pre + sum;
}

// pass A: bin instances into 32 coarse buckets (256 targets each), LDS-sorted, coalesced run writes
#define CHUNK 2048
__global__ __launch_bounds__(256) void binA_kernel(
    const int* __restrict__ tgt_user, const int* __restrict__ tgt_item,
    const int* __restrict__ emi_user, const int* __restrict__ emi_item,
    int* __restrict__ cur32, ushort4* __restrict__ binbuf)
{
    int combo = blockIdx.y;
    const int* tgt = (combo < 2 ? tgt_user : tgt_item) + (long)(combo & 1) * EEE;
    const int* emi = (combo < 2 ? emi_user : emi_item) + (long)(combo & 1) * EEE * 3;
    __shared__ ushort4 sbuf[CHUNK];
    __shared__ int lcnt[32], lofs[33], gbase[32], lcur[32];
    int tid = threadIdx.x;
    int base = blockIdx.x * CHUNK;
    if (tid < 32) { lcnt[tid] = 0; lcur[tid] = 0; }
    __syncthreads();
    ushort4 ent[8]; int bk[8];
#pragma unroll
    for (int ps = 0; ps < 8; ps++) {
        int i = base + ps * 256 + tid;
        if (i < EEE) {
            int t = tgt[i];
            ent[ps] = make_ushort4((unsigned short)emi[3 * i], (unsigned short)emi[3 * i + 1],
                                   (unsigned short)emi[3 * i + 2], (unsigned short)t);
            bk[ps] = t >> 8;
            atomicAdd(&lcnt[bk[ps]], 1);
        } else bk[ps] = -1;
    }
    __syncthreads();
    if (tid == 0) {
        int run = 0;
        for (int k = 0; k < 32; k++) { lofs[k] = run; run += lcnt[k]; }
        lofs[32] = run;
    }
    __syncthreads();
    if (tid < 32) gbase[tid] = atomicAdd(&cur32[combo * 32 + tid], lcnt[tid]);
    __syncthreads();
#pragma unroll
    for (int ps = 0; ps < 8; ps++) {
        if (bk[ps] >= 0) {
            int pos = lofs[bk[ps]] + atomicAdd(&lcur[bk[ps]], 1);
            sbuf[pos] = ent[ps];
        }
    }
    __syncthreads();
    int total = lofs[32];
    ushort4* dst = binbuf + (long)combo * EEE;
    for (int j = tid; j < total; j += 256) {
        ushort4 e = sbuf[j];
        int k = e.w >> 8;
        dst[gbase[k] + (j - lofs[k])] = e;
    }
}

// pass B: within each coarse bucket (contiguous ~50KB window), place entries at exact CSR position
__global__ __launch_bounds__(256) void binB_kernel(
    const int* __restrict__ offs, int* __restrict__ cur,
    const ushort4* __restrict__ binbuf, ushort4* __restrict__ nodes)
{
    int combo = blockIdx.y;
    int k = blockIdx.x >> 1, part = blockIdx.x & 1;
    const int* of = offs + combo * (BBB + 1);
    int rbeg = of[k << 8], rend = of[(k + 1) << 8];
    const ushort4* src = binbuf + (long)combo * EEE;
    ushort4* dst = nodes + (long)combo * EEE;
    int* cu = cur + combo * BBB;
    for (int j = rbeg + part * 256 + threadIdx.x; j < rend; j += 512) {
        ushort4 e = src[j];
        int t = e.w;
        int pos = of[t] + atomicAdd(&cu[t], 1);
        dst[pos] = e;
    }
}

// ---------------- flash metapath: gather + rotate + attention + online softmax + ELU ----------------
__global__ __launch_bounds__(256) void flash_mp(
    const __hip_bfloat16* __restrict__ feat, const ushort4* __restrict__ nodes,
    const int* __restrict__ offs, const float* __restrict__ r_vec,
    const float* __restrict__ attn_user, const float* __restrict__ attn_item,
    float* __restrict__ ret)
{
    int combo = blockIdx.y;
    int wid = threadIdx.x >> 6, lane = threadIdx.x & 63;
    int half = lane >> 5, p = lane & 31;
    int side = combo >> 1;
    const float* attn = (side == 0 ? attn_user : attn_item) + (combo & 1) * 64;
    const __hip_bfloat162* f2 = (const __hip_bfloat162*)feat;
    float2 rb = ((const float2*)r_vec)[p];
    float invn = 1.f / sqrtf(rb.x * rb.x + rb.y * rb.y);
    float rvx = rb.x * invn, rvy = rb.y * invn;
    if (side == 0) rvy = -rvy;
    float aRe = attn[2 * p], aIm = attn[2 * p + 1];
    int t = blockIdx.x * 4 + wid;
    int beg = offs[combo * (BBB + 1) + t], end = offs[combo * (BBB + 1) + t + 1];
    int n = end - beg;
    const ushort4* nd = nodes + (long)combo * EEE;

    float m = -3.4e38f, s = 0.f, Ox = 0.f, Oy = 0.f;

    __hip_bfloat162 c[8][3];
    ushort4 nq[8];
    if (n > 0) {
#pragma unroll
        for (int q = 0; q < 8; q++) {
            int j = beg + 2 * q + half; if (j >= end) j = end - 1;
            ushort4 a = nd[j];
            c[q][0] = f2[(int)a.x * 32 + p];
            c[q][1] = f2[(int)a.y * 32 + p];
            c[q][2] = f2[(int)a.z * 32 + p];
        }
#pragma unroll
        for (int q = 0; q < 8; q++) {
            int j = beg + 16 + 2 * q + half; if (j >= end) j = end - 1;
            nq[q] = nd[j];
        }
    }
    for (int it = 0; it < n; it += 16) {
        float2 u[8][3];
#pragma unroll
        for (int q = 0; q < 8; q++)
#pragma unroll
            for (int r = 0; r < 3; r++)
                u[q][r] = __bfloat1622float2(c[q][r]);
        if (it + 16 < n) {
#pragma unroll
            for (int q = 0; q < 8; q++) {
                c[q][0] = f2[(int)nq[q].x * 32 + p];
                c[q][1] = f2[(int)nq[q].y * 32 + p];
                c[q][2] = f2[(int)nq[q].z * 32 + p];
            }
#pragma unroll
            for (int q = 0; q < 8; q++) {
                int j = beg + it + 32 + 2 * q + half; if (j >= end) j = end - 1;
                nq[q] = nd[j];
            }
        }
        float re[8], im[8], e[8];
#pragma unroll
        for (int q = 0; q < 8; q++) {
            re[q] = (u[q][0].x + u[q][2].x + u[q][1].x * rvx - u[q][1].y * rvy) * (1.f / 3.f);
            im[q] = (u[q][0].y + u[q][2].y + u[q][1].x * rvy + u[q][1].y * rvx) * (1.f / 3.f);
            float pa = re[q] * aRe + im[q] * aIm;
            pa += __shfl_xor(pa, 1);
            pa += __shfl_xor(pa, 2);
            float ev = pa > 0.f ? pa : 0.01f * pa;       // leaky_relu
            if (it + 2 * q + half >= n) ev = -3.4e38f;
            e[q] = ev;
        }
        float mx = e[0];
#pragma unroll
        for (int q = 1; q < 8; q++) mx = fmaxf(mx, e[q]);
        float mn = fmaxf(m, fmaxf(mx, __shfl_xor(mx, 32)));
        float alpha = __expf(m - mn);
        float wl = 0.f, ax = 0.f, ay = 0.f;
#pragma unroll
        for (int q = 0; q < 8; q++) {
            float w = __expf(e[q] - mn);
            wl += w; ax = fmaf(w, re[q], ax); ay = fmaf(w, im[q], ay);
        }
        s = s * alpha + wl + __shfl_xor(wl, 32);
        Ox = Ox * alpha + ax;
        Oy = Oy * alpha + ay;
        m = mn;
    }
    float sx = __shfl_xor(Ox, 32), sy = __shfl_xor(Oy, 32);
    float inv = 1.f / (s + 1e-9f);
    float vx = (Ox + sx) * inv, vy = (Oy + sy) * inv;
    vx = vx > 0.f ? vx : __expf(vx) - 1.f;   // ELU
    vy = vy > 0.f ? vy : __expf(vy) - 1.f;
    if (half == 0)
        ((float2*)ret)[((long)combo * BBB + t) * 32 + p] = make_float2(vx, vy);
}

// ---------------- semantic score GEMM: s_acc[combo] = sum_b tanh(ret_b @ w1 + b1) @ w2 ----------------
__global__ __launch_bounds__(256) void sem_kernel(
    const float* __restrict__ ret,
    const float* __restrict__ su_w1, const float* __restrict__ su_b1, const float* __restrict__ su_w2,
    const float* __restrict__ si_w1, const float* __restrict__ si_b1, const float* __restrict__ si_w2,
    float* __restrict__ s_acc)
{
    int combo = blockIdx.y;
    int side = combo >> 1;
    const float* w1 = side ? si_w1 : su_w1;
    const float* b1 = side ? si_b1 : su_b1;
    const float* w2 = side ? si_w2 : su_w2;
    __shared__ float vs[64][68];
    __shared__ float w1s[64][128];
    int tid = threadIdx.x;
    int rowbase = blockIdx.x * 64;
    const float4* r4 = (const float4*)ret;
    for (int li = tid; li < 1024; li += 256) {
        int r = li >> 4, c4 = li & 15;
        float4 v = r4[((long)combo * BBB + rowbase + r) * 16 + c4];
        *(float4*)&vs[r][c4 * 4] = v;
    }
    const float4* w14 = (const float4*)w1;
    for (int li = tid; li < 2048; li += 256) {
        float4 v = w14[li];
        *(float4*)&w1s[li >> 5][(li & 31) * 4] = v;
    }
    __syncthreads();
    int ct = tid & 15, rt = tid >> 4;
    float acc[4][8];
#pragma unroll
    for (int cc = 0; cc < 8; cc++) {
        float b = b1[8 * ct + cc];
#pragma unroll
        for (int j = 0; j < 4; j++) acc[j][cc] = b;
    }
    for (int k = 0; k < 64; k += 4) {
        float4 xv[4];
#pragma unroll
        for (int j = 0; j < 4; j++) xv[j] = *(const float4*)&vs[4 * rt + j][k];
#pragma unroll
        for (int kk = 0; kk < 4; kk++) {
            float4 wv0 = *(const float4*)&w1s[k + kk][8 * ct];
            float4 wv1 = *(const float4*)&w1s[k + kk][8 * ct + 4];
#pragma unroll
            for (int j = 0; j < 4; j++) {
                float xx = kk == 0 ? xv[j].x : kk == 1 ? xv[j].y : kk == 2 ? xv[j].z : xv[j].w;
                acc[j][0] = fmaf(xx, wv0.x, acc[j][0]);
                acc[j][1] = fmaf(xx, wv0.y, acc[j][1]);
                acc[j][2] = fmaf(xx, wv0.z, acc[j][2]);
                acc[j][3] = fmaf(xx, wv0.w, acc[j][3]);
                acc[j][4] = fmaf(xx, wv1.x, acc[j][4]);
                acc[j][5] = fmaf(xx, wv1.y, acc[j][5]);
                acc[j][6] = fmaf(xx, wv1.z, acc[j][6]);
                acc[j][7] = fmaf(xx, wv1.w, acc[j][7]);
            }
        }
    }
    float tot = 0.f;
#pragma unroll
    for (int cc = 0; cc < 8; cc++) {
        float w2v = w2[8 * ct + cc];
#pragma unroll
        for (int j = 0; j < 4; j++) tot += fast_tanh(acc[j][cc]) * w2v;
    }
    for (int off = 32; off; off >>= 1) tot += __shfl_xor(tot, off);
    __shared__ float red[4];
    int lane = tid & 63, wid = tid >> 6;
    if (lane == 0) red[wid] = tot;
    __syncthreads();
    if (tid == 0) atomicAdd(&s_acc[combo], red[0] + red[1] + red[2] + red[3]);
}

// ---------------- final product MLP + softmax (beta inline, GEMM-tiled) ----------------
__global__ __launch_bounds__(256) void final_kernel(
    const float* __restrict__ ret, const float* __restrict__ s_acc,
    const float* __restrict__ cw1, const float* __restrict__ cb1, const float* __restrict__ cw2,
    float* __restrict__ outp)
{
    float s0 = s_acc[0] * (1.f / BBB), s1 = s_acc[1] * (1.f / BBB);
    float s2 = s_acc[2] * (1.f / BBB), s3 = s_acc[3] * (1.f / BBB);
    float mu = fmaxf(s0, s1);
    float e0 = __expf(s0 - mu), e1 = __expf(s1 - mu);
    float bu0 = e0 / (e0 + e1), bu1 = e1 / (e0 + e1);
    float mi = fmaxf(s2, s3);
    float f0 = __expf(s2 - mi), f1 = __expf(s3 - mi);
    float bi0 = f0 / (f0 + f1), bi1 = f1 / (f0 + f1);

    __shared__ float xsld[64][68];
    __shared__ float w1s[64][128];
    int tid = threadIdx.x;
    int rowbase = blockIdx.x * 64;
    const float4* r4 = (const float4*)ret;
    for (int li = tid; li < 1024; li += 256) {
        int r = li >> 4, c4 = li & 15;
        float4 a = r4[((long)0 * BBB + rowbase + r) * 16 + c4];
        float4 b = r4[((long)1 * BBB + rowbase + r) * 16 + c4];
        float4 cc = r4[((long)2 * BBB + rowbase + r) * 16 + c4];
        float4 d = r4[((long)3 * BBB + rowbase + r) * 16 + c4];
        float4 xv;
        xv.x = (bu0 * a.x + bu1 * b.x) * (bi0 * cc.x + bi1 * d.x);
        xv.y = (bu0 * a.y + bu1 * b.y) * (bi0 * cc.y + bi1 * d.y);
        xv.z = (bu0 * a.z + bu1 * b.z) * (bi0 * cc.z + bi1 * d.z);
        xv.w = (bu0 * a.w + bu1 * b.w) * (bi0 * cc.w + bi1 * d.w);
        *(float4*)&xsld[r][c4 * 4] = xv;
    }
    const float4* w14 = (const float4*)cw1;
    for (int li = tid; li < 2048; li += 256) {
        float4 v = w14[li];
        *(float4*)&w1s[li >> 5][(li & 31) * 4] = v;
    }
    __syncthreads();
    int ct = tid & 15, rt = tid >> 4;
    float acc[4][8];
#pragma unroll
    for (int cc = 0; cc < 8; cc++) {
        float b = cb1[8 * ct + cc];
#pragma unroll
        for (int j = 0; j < 4; j++) acc[j][cc] = b;
    }
    for (int k = 0; k < 64; k += 4) {
        float4 xv[4];
#pragma unroll
        for (int j = 0; j < 4; j++) xv[j] = *(const float4*)&xsld[4 * rt + j][k];
#pragma unroll
        for (int kk = 0; kk < 4; kk++) {
            float4 wv0 = *(const float4*)&w1s[k + kk][8 * ct];
            float4 wv1 = *(const float4*)&w1s[k + kk][8 * ct + 4];
#pragma unroll
            for (int j = 0; j < 4; j++) {
                float xx = kk == 0 ? xv[j].x : kk == 1 ? xv[j].y : kk == 2 ? xv[j].z : xv[j].w;
                acc[j][0] = fmaf(xx, wv0.x, acc[j][0]);
                acc[j][1] = fmaf(xx, wv0.y, acc[j][1]);
                acc[j][2] = fmaf(xx, wv0.z, acc[j][2]);
                acc[j][3] = fmaf(xx, wv0.w, acc[j][3]);
                acc[j][4] = fmaf(xx, wv1.x, acc[j][4]);
                acc[j][5] = fmaf(xx, wv1.y, acc[j][5]);
                acc[j][6] = fmaf(xx, wv1.z, acc[j][6]);
                acc[j][7] = fmaf(xx, wv1.w, acc[j][7]);
            }
        }
    }
    float pp0[4], pp1[4];
#pragma unroll
    for (int j = 0; j < 4; j++) { pp0[j] = 0.f; pp1[j] = 0.f; }
#pragma unroll
    for (int cc = 0; cc < 8; cc++) {
        int col = 8 * ct + cc;
        float c0 = cw2[col * 2], c1 = cw2[col * 2 + 1];
#pragma unroll
        for (int j = 0; j < 4; j++) {
            float h = fmaxf(acc[j][cc], 0.f);
            pp0[j] = fmaf(h, c0, pp0[j]);
            pp1[j] = fmaf(h, c1, pp1[j]);
        }
    }
    __syncthreads();
    float2* red = (float2*)xsld;
#pragma unroll
    for (int j = 0; j < 4; j++)
        red[(4 * rt + j) * 16 + ct] = make_float2(pp0[j], pp1[j]);
    __syncthreads();
    if (tid < 64) {
        float q0 = 0.f, q1 = 0.f;
        for (int i = 0; i < 16; i++) {
            float2 e = red[tid * 16 + i];
            q0 += e.x; q1 += e.y;
        }
        float mx = fmaxf(q0, q1);
        float a0 = __expf(q0 - mx), a1 = __expf(q1 - mx);
        float dn = a0 + a1;
        outp[(rowbase + tid) * 2] = a0 / dn;
        outp[(rowbase + tid) * 2 + 1] = a1 / dn;
    }
}

extern "C" void kernel_launch(void* const* d_in, const int* in_sizes, int n_in,
                              void* d_out, int out_size, void* d_ws, size_t ws_size,
                              hipStream_t stream)
{
    const float* feats0 = (const float*)d_in[0];
    const float* feats1 = (const float*)d_in[1];
    const float* t0_pw = (const float*)d_in[2];
    const float* t0_pb = (const float*)d_in[3];
    const float* t0_w2 = (const float*)d_in[4];
    const float* t0_b2 = (const float*)d_in[5];
    const float* t0_g  = (const float*)d_in[6];
    const float* t0_be = (const float*)d_in[7];
    const float* t1_pw = (const float*)d_in[8];
    const float* t1_pb = (const float*)d_in[9];
    const float* t1_w2 = (const float*)d_in[10];
    const float* t1_b2 = (const float*)d_in[11];
    const float* t1_g  = (const float*)d_in[12];
    const float* t1_be = (const float*)d_in[13];
    const float* r_vec = (const float*)d_in[14];
    const float* attn_user = (const float*)d_in[15];
    const float* attn_item = (const float*)d_in[16];
    const float* su_w1 = (const float*)d_in[17];
    const float* su_b1 = (const float*)d_in[18];
    const float* su_w2 = (const float*)d_in[19];
    const float* si_w1 = (const float*)d_in[20];
    const float* si_b1 = (const float*)d_in[21];
    const float* si_w2 = (const float*)d_in[22];
    const float* cw1 = (const float*)d_in[23];
    const float* cb1 = (const float*)d_in[24];
    const float* cw2 = (const float*)d_in[25];
    const int* idx0 = (const int*)d_in[26];
    const int* idx1 = (const int*)d_in[27];
    const int* emi_user = (const int*)d_in[28];
    const int* tgt_user = (const int*)d_in[29];
    const int* emi_item = (const int*)d_in[30];
    const int* tgt_item = (const int*)d_in[31];
    float* outp = (float*)d_out;

    // workspace layout (256B aligned)
    char* ws = (char*)d_ws;
    __hip_bfloat16* feat = (__hip_bfloat16*)(ws + 0);   // 5,120,000
    int*     cnt    = (int*)(ws + 5120000);             // 131,072
    int*     cur    = (int*)(ws + 5251072);             // 131,072 (contiguous with cnt for one memset)
    int*     cur32  = (int*)(ws + 5382144);             // 512
    int*     offs   = (int*)(ws + 5382656);             // 131,088 -> pad 131,328
    float*   s_acc  = (float*)(ws + 5513984);           // 256
    ushort4* binbuf = (ushort4*)(ws + 5514240);         // 6,400,000
    ushort4* nodes  = (ushort4*)(ws + 11914240);        // 6,400,000
    float*   ret_buf= (float*)(ws + 18314240);          // 8,388,608
    __bf16*  wprep  = (__bf16*)(ws + 26702848);         // 262,144  (end ~27.0 MB)

    prep_w<<<2, 256, 0, stream>>>(t0_pw, t1_pw, wprep);

    tower_kernel<<<dim3((NN0 + 63) / 64, 2), 256, 0, stream>>>(
        feats0, feats1, wprep, t0_pb, t1_pb, t0_w2, t1_w2,
        t0_b2, t1_b2, t0_g, t1_g, t0_be, t1_be, idx0, idx1, feat);

    hipMemsetAsync(cnt, 0, 2 * 4 * BBB * sizeof(int), stream);
    hist_kernel<<<dim3((EEE + 255) / 256, 4), 256, 0, stream>>>(tgt_user, tgt_item, cnt);
    scan_kernel<<<4, 256, 0, stream>>>(cnt, offs, cur32, s_acc);
    binA_kernel<<<dim3((EEE + CHUNK - 1) / CHUNK, 4), 256, 0, stream>>>(
        tgt_user, tgt_item, emi_user, emi_item, cur32, binbuf);
    binB_kernel<<<dim3(64, 4), 256, 0, stream>>>(offs, cur, binbuf, nodes);

    flash_mp<<<dim3(BBB / 4, 4), 256, 0, stream>>>(feat, nodes, offs, r_vec,
                                                   attn_user, attn_item, ret_buf);

    sem_kernel<<<dim3(BBB / 64, 4), 256, 0, stream>>>(ret_buf, su_w1, su_b1, su_w2,
                                                      si_w1, si_b1, si_w2, s_acc);
    final_kernel<<<BBB / 64, 256, 0, stream>>>(ret_buf, s_acc, cw1, cb1, cw2, outp);
}

// Round 2
// 355.332 us; speedup vs baseline: 1.1927x; 1.1927x over previous
//
#include <hip/hip_runtime.h>
#include <hip/hip_bf16.h>
#include <math.h>

// MAGNN link prediction forward — fp32 compute; feat table stored bf16.
// Tower: barrier-free per-wave MFMA GEMM (split-bf16 hi/lo, 3 MFMAs ~ fp32 accuracy).
#define NN0 20000
#define NN1 20000
#define NTOT 40000
#define FF0 512
#define HIDD 64
#define EEE 200000
#define BBB 8192
#define AVV 128
#define CHH 128

typedef __bf16 bf16x8 __attribute__((ext_vector_type(8)));
typedef __bf16 bf16x4 __attribute__((ext_vector_type(4)));
typedef float f32x4 __attribute__((ext_vector_type(4)));

__device__ __forceinline__ float fast_tanh(float x) {
    float e2 = __expf(2.f * x);
    return 1.f - 2.f / (e2 + 1.f);
}

// ---------------- weight prep: hi/lo bf16 split into exact B-fragment order ----------------
// GEMM1 (pw [512][64]): fragment element (ks, nt, lane, j) holds w[k][n] with
//   k = ks*32 + (lane>>4)*8 + j, n = nt*16 + (lane&15).
// hi at [((ks*4+nt)*64 + lane)*8 + j], lo at +32768 (per tower: 65536 bf16 = 128KB).
// GEMM2 (w2 [64][64]): same formula, ks in 0..1; per tower 8192 bf16 = 16KB.
__global__ __launch_bounds__(256) void prep_w(
    const float* __restrict__ pw0, const float* __restrict__ pw1,
    const float* __restrict__ w20, const float* __restrict__ w21,
    __bf16* __restrict__ wprep, __bf16* __restrict__ w2prep)
{
    int tw = blockIdx.x;
    int seg = blockIdx.y;                    // 0..7
    const float* w = tw ? pw1 : pw0;
    __bf16* base = wprep + tw * 65536;
    for (int idx = seg * 4096 + threadIdx.x; idx < (seg + 1) * 4096; idx += 256) {
        int k = idx >> 6, n = idx & 63;      // w[k][n], row-major [512][64]
        float v = w[idx];
        __bf16 hi = (__bf16)v;
        __bf16 lo = (__bf16)(v - (float)hi);
        int ks = k >> 5, kb = (k >> 3) & 3, j = k & 7;
        int nt = n >> 4, fr = n & 15;
        int lane = kb * 16 + fr;
        int off = ((ks * 4 + nt) * 64 + lane) * 8 + j;
        base[off] = hi;
        base[32768 + off] = lo;
    }
    const float* w2 = tw ? w21 : w20;
    __bf16* base2 = w2prep + tw * 8192;
    for (int idx = seg * 512 + threadIdx.x; idx < (seg + 1) * 512; idx += 256) {
        int k = idx >> 6, n = idx & 63;      // w2[k][n], [64][64]
        float v = w2[idx];
        __bf16 hi = (__bf16)v;
        __bf16 lo = (__bf16)(v - (float)hi);
        int ks = k >> 5, kb = (k >> 3) & 3, j = k & 7;
        int nt = n >> 4, fr = n & 15;
        int lane = kb * 16 + fr;
        int off = ((ks * 4 + nt) * 64 + lane) * 8 + j;
        base2[off] = hi;
        base2[4096 + off] = lo;
    }
}

// ---------------- tower: per-wave MFMA, no barriers in K-loop ----------------
// 1 wave per block; wave owns 16 rows x 64 cols, full K=512.
// A fragments direct from global fp32 x (convert in-register, hi/lo split).
// B fragments direct from prepacked global image (L2-resident).
// GEMM2 via 4.4KB per-wave LDS transpose of h; residual in accumulator init; LN in-register.
__global__ __launch_bounds__(64) void tower_kernel(
    const float* __restrict__ x0, const float* __restrict__ x1,
    const __bf16* __restrict__ wprep, const __bf16* __restrict__ w2prep,
    const float* __restrict__ pb0, const float* __restrict__ pb1,
    const float* __restrict__ b20, const float* __restrict__ b21,
    const float* __restrict__ g0, const float* __restrict__ g1,
    const float* __restrict__ be0, const float* __restrict__ be1,
    const int* __restrict__ idxa, const int* __restrict__ idxb,
    __hip_bfloat16* __restrict__ feat)
{
    int tw = blockIdx.y;
    const float* x  = tw ? x1 : x0;
    const float* pb = tw ? pb1 : pb0;
    const float* b2 = tw ? b21 : b20;
    const float* g  = tw ? g1 : g0;
    const float* be = tw ? be1 : be0;
    const int* idx  = tw ? idxb : idxa;

    __shared__ float hs[16][68];

    int l = threadIdx.x;                     // 0..63
    int fr = l & 15, kb = l >> 4;
    int row0 = blockIdx.x * 16;              // 1250 * 16 = 20000 exactly, no tail
    const float* xp = x + (long)(row0 + fr) * FF0 + kb * 8;
    const __bf16* bp = wprep + tw * 65536;

    f32x4 acc[4];
#pragma unroll
    for (int nt = 0; nt < 4; nt++) acc[nt] = (f32x4){0.f, 0.f, 0.f, 0.f};

    // register double-buffer: current / next
    float4 a0c, a1c, a0n, a1n;
    bf16x8 bhc[4], blc[4], bhn[4], bln[4];

    a0c = *(const float4*)xp;
    a1c = *(const float4*)(xp + 4);
#pragma unroll
    for (int nt = 0; nt < 4; nt++) {
        bhc[nt] = *(const bf16x8*)(bp + (nt * 64 + l) * 8);
        blc[nt] = *(const bf16x8*)(bp + 32768 + (nt * 64 + l) * 8);
    }

#pragma unroll 2
    for (int ks = 0; ks < 16; ks++) {
        if (ks + 1 < 16) {
            a0n = *(const float4*)(xp + (ks + 1) * 32);
            a1n = *(const float4*)(xp + (ks + 1) * 32 + 4);
#pragma unroll
            for (int nt = 0; nt < 4; nt++) {
                bhn[nt] = *(const bf16x8*)(bp + (((ks + 1) * 4 + nt) * 64 + l) * 8);
                bln[nt] = *(const bf16x8*)(bp + 32768 + (((ks + 1) * 4 + nt) * 64 + l) * 8);
            }
        }
        float av[8] = {a0c.x, a0c.y, a0c.z, a0c.w, a1c.x, a1c.y, a1c.z, a1c.w};
        bf16x8 ah, al;
#pragma unroll
        for (int j = 0; j < 8; j++) {
            __bf16 h = (__bf16)av[j];
            ah[j] = h;
            al[j] = (__bf16)(av[j] - (float)h);
        }
#pragma unroll
        for (int nt = 0; nt < 4; nt++) {
            acc[nt] = __builtin_amdgcn_mfma_f32_16x16x32_bf16(ah, bhc[nt], acc[nt], 0, 0, 0);
            acc[nt] = __builtin_amdgcn_mfma_f32_16x16x32_bf16(al, bhc[nt], acc[nt], 0, 0, 0);
            acc[nt] = __builtin_amdgcn_mfma_f32_16x16x32_bf16(ah, blc[nt], acc[nt], 0, 0, 0);
        }
        a0c = a0n; a1c = a1n;
#pragma unroll
        for (int nt = 0; nt < 4; nt++) { bhc[nt] = bhn[nt]; blc[nt] = bln[nt]; }
    }

    // ---- epilogue 1: z = acc + pb; h = gelu(z) -> hs; acc2 = z + b2 ----
    // C layout: col = nt*16 + (lane&15), row = (lane>>4)*4 + j   [m89-verified]
    float pbv[4], b2v[4];
#pragma unroll
    for (int nt = 0; nt < 4; nt++) { pbv[nt] = pb[nt * 16 + fr]; b2v[nt] = b2[nt * 16 + fr]; }
    f32x4 acc2[4];
#pragma unroll
    for (int nt = 0; nt < 4; nt++) {
#pragma unroll
        for (int j = 0; j < 4; j++) {
            float z = acc[nt][j] + pbv[nt];
            float h = 0.5f * z * (1.f + erff(z * 0.70710678118654752f));
            hs[kb * 4 + j][nt * 16 + fr] = h;
            acc2[nt][j] = z + b2v[nt];
        }
    }
    __syncthreads();   // single wave: orders LDS write->read

    // ---- GEMM2 (MFMA): y = h@w2 + b2 + z ----
    const __bf16* w2p = w2prep + tw * 8192;
#pragma unroll
    for (int ks = 0; ks < 2; ks++) {
        float4 h0 = *(const float4*)&hs[fr][ks * 32 + kb * 8];
        float4 h1 = *(const float4*)&hs[fr][ks * 32 + kb * 8 + 4];
        float hv[8] = {h0.x, h0.y, h0.z, h0.w, h1.x, h1.y, h1.z, h1.w};
        bf16x8 ah, al;
#pragma unroll
        for (int j = 0; j < 8; j++) {
            __bf16 h = (__bf16)hv[j];
            ah[j] = h;
            al[j] = (__bf16)(hv[j] - (float)h);
        }
#pragma unroll
        for (int nt = 0; nt < 4; nt++) {
            bf16x8 bh2 = *(const bf16x8*)(w2p + ((ks * 4 + nt) * 64 + l) * 8);
            bf16x8 bl2 = *(const bf16x8*)(w2p + 4096 + ((ks * 4 + nt) * 64 + l) * 8);
            acc2[nt] = __builtin_amdgcn_mfma_f32_16x16x32_bf16(ah, bh2, acc2[nt], 0, 0, 0);
            acc2[nt] = __builtin_amdgcn_mfma_f32_16x16x32_bf16(al, bh2, acc2[nt], 0, 0, 0);
            acc2[nt] = __builtin_amdgcn_mfma_f32_16x16x32_bf16(ah, bl2, acc2[nt], 0, 0, 0);
        }
    }
    __syncthreads();   // hs reads done; reuse hs for normalized output

    // ---- LayerNorm in-register: row r = kb*4+j lives on the 16 lanes of group kb ----
    float gv[4], bev[4];
#pragma unroll
    for (int nt = 0; nt < 4; nt++) { gv[nt] = g[nt * 16 + fr]; bev[nt] = be[nt * 16 + fr]; }
#pragma unroll
    for (int j = 0; j < 4; j++) {
        float p = acc2[0][j] + acc2[1][j] + acc2[2][j] + acc2[3][j];
        p += __shfl_xor(p, 1); p += __shfl_xor(p, 2);
        p += __shfl_xor(p, 4); p += __shfl_xor(p, 8);
        float mu = p * (1.f / 64.f);
        float d[4], vs = 0.f;
#pragma unroll
        for (int nt = 0; nt < 4; nt++) { d[nt] = acc2[nt][j] - mu; vs += d[nt] * d[nt]; }
        vs += __shfl_xor(vs, 1); vs += __shfl_xor(vs, 2);
        vs += __shfl_xor(vs, 4); vs += __shfl_xor(vs, 8);
        float is = 1.f / sqrtf(vs * (1.f / 64.f) + 1e-5f);
#pragma unroll
        for (int nt = 0; nt < 4; nt++)
            hs[kb * 4 + j][nt * 16 + fr] = d[nt] * is * gv[nt] + bev[nt];
    }
    __syncthreads();
    // coalesced bf16 store: lane = col
#pragma unroll 4
    for (int r = 0; r < 16; r++) {
        int grow = row0 + r;
        feat[(long)idx[grow] * HIDD + l] = __float2bfloat16(hs[r][l]);
    }
}

// ---------------- CSR build: hist -> scan -> binA (coarse) -> binB (exact) ----------------
__global__ void hist_kernel(const int* __restrict__ tgt_user, const int* __restrict__ tgt_item,
                            int* __restrict__ cnt)
{
    int combo = blockIdx.y;
    const int* tgt = (combo < 2 ? tgt_user : tgt_item) + (long)(combo & 1) * EEE;
    int i = blockIdx.x * 256 + threadIdx.x;
    if (i < EEE) atomicAdd(&cnt[combo * BBB + tgt[i]], 1);
}

__global__ __launch_bounds__(256) void scan_kernel(const int* __restrict__ cnt, int* __restrict__ offs,
                                                   int* __restrict__ cur32, float* __restrict__ s_acc)
{
    int pth = blockIdx.x;
    if (pth == 0 && threadIdx.x < 4) s_acc[threadIdx.x] = 0.f;
    const int* c = cnt + pth * BBB;
    int* o = offs + pth * (BBB + 1);
    __shared__ int part[256];
    int tid = threadIdx.x;
    int base = tid * 32;
    int local[32];
    int sum = 0;
    for (int j = 0; j < 32; j++) { local[j] = sum; sum += c[base + j]; }
    part[tid] = sum;
    __syncthreads();
    for (int d = 1; d < 256; d <<= 1) {
        int v = (tid >= d) ? part[tid - d] : 0;
        __syncthreads();
        part[tid] += v;
        __syncthreads();
    }
    int pre = (tid == 0) ? 0 : part[tid - 1];
    for (int j = 0; j < 32; j++) {
        int val = pre + local[j];
        o[base + j] = val;
        if (((base + j) & 255) == 0) cur32[pth * 32 + ((base + j) >> 8)] = val;
    }
    if (tid == 255) o[BBB] = pre + sum;
}

// pass A: bin instances into 32 coarse buckets (256 targets each), LDS-sorted, coalesced run writes
#define CHUNK 2048
__global__ __launch_bounds__(256) void binA_kernel(
    const int* __restrict__ tgt_user, const int* __restrict__ tgt_item,
    const int* __restrict__ emi_user, const int* __restrict__ emi_item,
    int* __restrict__ cur32, ushort4* __restrict__ binbuf)
{
    int combo = blockIdx.y;
    const int* tgt = (combo < 2 ? tgt_user : tgt_item) + (long)(combo & 1) * EEE;
    const int* emi = (combo < 2 ? emi_user : emi_item) + (long)(combo & 1) * EEE * 3;
    __shared__ ushort4 sbuf[CHUNK];
    __shared__ int lcnt[32], lofs[33], gbase[32], lcur[32];
    int tid = threadIdx.x;
    int base = blockIdx.x * CHUNK;
    if (tid < 32) { lcnt[tid] = 0; lcur[tid] = 0; }
    __syncthreads();
    ushort4 ent[8]; int bk[8];
#pragma unroll
    for (int ps = 0; ps < 8; ps++) {
        int i = base + ps * 256 + tid;
        if (i < EEE) {
            int t = tgt[i];
            ent[ps] = make_ushort4((unsigned short)emi[3 * i], (unsigned short)emi[3 * i + 1],
                                   (unsigned short)emi[3 * i + 2], (unsigned short)t);
            bk[ps] = t >> 8;
            atomicAdd(&lcnt[bk[ps]], 1);
        } else bk[ps] = -1;
    }
    __syncthreads();
    if (tid == 0) {
        int run = 0;
        for (int k = 0; k < 32; k++) { lofs[k] = run; run += lcnt[k]; }
        lofs[32] = run;
    }
    __syncthreads();
    if (tid < 32) gbase[tid] = atomicAdd(&cur32[combo * 32 + tid], lcnt[tid]);
    __syncthreads();
#pragma unroll
    for (int ps = 0; ps < 8; ps++) {
        if (bk[ps] >= 0) {
            int pos = lofs[bk[ps]] + atomicAdd(&lcur[bk[ps]], 1);
            sbuf[pos] = ent[ps];
        }
    }
    __syncthreads();
    int total = lofs[32];
    ushort4* dst = binbuf + (long)combo * EEE;
    for (int j = tid; j < total; j += 256) {
        ushort4 e = sbuf[j];
        int k = e.w >> 8;
        dst[gbase[k] + (j - lofs[k])] = e;
    }
}

// pass B: within each coarse bucket (contiguous ~50KB window), place entries at exact CSR position
__global__ __launch_bounds__(256) void binB_kernel(
    const int* __restrict__ offs, int* __restrict__ cur,
    const ushort4* __restrict__ binbuf, ushort4* __restrict__ nodes)
{
    int combo = blockIdx.y;
    int k = blockIdx.x >> 1, part = blockIdx.x & 1;
    const int* of = offs + combo * (BBB + 1);
    int rbeg = of[k << 8], rend = of[(k + 1) << 8];
    const ushort4* src = binbuf + (long)combo * EEE;
    ushort4* dst = nodes + (long)combo * EEE;
    int* cu = cur + combo * BBB;
    for (int j = rbeg + part * 256 + threadIdx.x; j < rend; j += 512) {
        ushort4 e = src[j];
        int t = e.w;
        int pos = of[t] + atomicAdd(&cu[t], 1);
        dst[pos] = e;
    }
}

// ---------------- flash metapath: gather + rotate + attention + online softmax + ELU ----------------
__global__ __launch_bounds__(256) void flash_mp(
    const __hip_bfloat16* __restrict__ feat, const ushort4* __restrict__ nodes,
    const int* __restrict__ offs, const float* __restrict__ r_vec,
    const float* __restrict__ attn_user, const float* __restrict__ attn_item,
    float* __restrict__ ret)
{
    int combo = blockIdx.y;
    int wid = threadIdx.x >> 6, lane = threadIdx.x & 63;
    int half = lane >> 5, p = lane & 31;
    int side = combo >> 1;
    const float* attn = (side == 0 ? attn_user : attn_item) + (combo & 1) * 64;
    const __hip_bfloat162* f2 = (const __hip_bfloat162*)feat;
    float2 rb = ((const float2*)r_vec)[p];
    float invn = 1.f / sqrtf(rb.x * rb.x + rb.y * rb.y);
    float rvx = rb.x * invn, rvy = rb.y * invn;
    if (side == 0) rvy = -rvy;
    float aRe = attn[2 * p], aIm = attn[2 * p + 1];
    int t = blockIdx.x * 4 + wid;
    int beg = offs[combo * (BBB + 1) + t], end = offs[combo * (BBB + 1) + t + 1];
    int n = end - beg;
    const ushort4* nd = nodes + (long)combo * EEE;

    float m = -3.4e38f, s = 0.f, Ox = 0.f, Oy = 0.f;

    __hip_bfloat162 c[8][3];
    ushort4 nq[8];
    if (n > 0) {
#pragma unroll
        for (int q = 0; q < 8; q++) {
            int j = beg + 2 * q + half; if (j >= end) j = end - 1;
            ushort4 a = nd[j];
            c[q][0] = f2[(int)a.x * 32 + p];
            c[q][1] = f2[(int)a.y * 32 + p];
            c[q][2] = f2[(int)a.z * 32 + p];
        }
#pragma unroll
        for (int q = 0; q < 8; q++) {
            int j = beg + 16 + 2 * q + half; if (j >= end) j = end - 1;
            nq[q] = nd[j];
        }
    }
    for (int it = 0; it < n; it += 16) {
        float2 u[8][3];
#pragma unroll
        for (int q = 0; q < 8; q++)
#pragma unroll
            for (int r = 0; r < 3; r++)
                u[q][r] = __bfloat1622float2(c[q][r]);
        if (it + 16 < n) {
#pragma unroll
            for (int q = 0; q < 8; q++) {
                c[q][0] = f2[(int)nq[q].x * 32 + p];
                c[q][1] = f2[(int)nq[q].y * 32 + p];
                c[q][2] = f2[(int)nq[q].z * 32 + p];
            }
#pragma unroll
            for (int q = 0; q < 8; q++) {
                int j = beg + it + 32 + 2 * q + half; if (j >= end) j = end - 1;
                nq[q] = nd[j];
            }
        }
        float re[8], im[8], e[8];
#pragma unroll
        for (int q = 0; q < 8; q++) {
            re[q] = (u[q][0].x + u[q][2].x + u[q][1].x * rvx - u[q][1].y * rvy) * (1.f / 3.f);
            im[q] = (u[q][0].y + u[q][2].y + u[q][1].x * rvy + u[q][1].y * rvx) * (1.f / 3.f);
            float pa = re[q] * aRe + im[q] * aIm;
            pa += __shfl_xor(pa, 1);
            pa += __shfl_xor(pa, 2);
            float ev = pa > 0.f ? pa : 0.01f * pa;       // leaky_relu
            if (it + 2 * q + half >= n) ev = -3.4e38f;
            e[q] = ev;
        }
        float mx = e[0];
#pragma unroll
        for (int q = 1; q < 8; q++) mx = fmaxf(mx, e[q]);
        float mn = fmaxf(m, fmaxf(mx, __shfl_xor(mx, 32)));
        float alpha = __expf(m - mn);
        float wl = 0.f, ax = 0.f, ay = 0.f;
#pragma unroll
        for (int q = 0; q < 8; q++) {
            float w = __expf(e[q] - mn);
            wl += w; ax = fmaf(w, re[q], ax); ay = fmaf(w, im[q], ay);
        }
        s = s * alpha + wl + __shfl_xor(wl, 32);
        Ox = Ox * alpha + ax;
        Oy = Oy * alpha + ay;
        m = mn;
    }
    float sx = __shfl_xor(Ox, 32), sy = __shfl_xor(Oy, 32);
    float inv = 1.f / (s + 1e-9f);
    float vx = (Ox + sx) * inv, vy = (Oy + sy) * inv;
    vx = vx > 0.f ? vx : __expf(vx) - 1.f;   // ELU
    vy = vy > 0.f ? vy : __expf(vy) - 1.f;
    if (half == 0)
        ((float2*)ret)[((long)combo * BBB + t) * 32 + p] = make_float2(vx, vy);
}

// ---------------- semantic score GEMM: s_acc[combo] = sum_b tanh(ret_b @ w1 + b1) @ w2 ----------------
__global__ __launch_bounds__(256) void sem_kernel(
    const float* __restrict__ ret,
    const float* __restrict__ su_w1, const float* __restrict__ su_b1, const float* __restrict__ su_w2,
    const float* __restrict__ si_w1, const float* __restrict__ si_b1, const float* __restrict__ si_w2,
    float* __restrict__ s_acc)
{
    int combo = blockIdx.y;
    int side = combo >> 1;
    const float* w1 = side ? si_w1 : su_w1;
    const float* b1 = side ? si_b1 : su_b1;
    const float* w2 = side ? si_w2 : su_w2;
    __shared__ float vs[64][68];
    __shared__ float w1s[64][128];
    int tid = threadIdx.x;
    int rowbase = blockIdx.x * 64;
    const float4* r4 = (const float4*)ret;
    for (int li = tid; li < 1024; li += 256) {
        int r = li >> 4, c4 = li & 15;
        float4 v = r4[((long)combo * BBB + rowbase + r) * 16 + c4];
        *(float4*)&vs[r][c4 * 4] = v;
    }
    const float4* w14 = (const float4*)w1;
    for (int li = tid; li < 2048; li += 256) {
        float4 v = w14[li];
        *(float4*)&w1s[li >> 5][(li & 31) * 4] = v;
    }
    __syncthreads();
    int ct = tid & 15, rt = tid >> 4;
    float acc[4][8];
#pragma unroll
    for (int cc = 0; cc < 8; cc++) {
        float b = b1[8 * ct + cc];
#pragma unroll
        for (int j = 0; j < 4; j++) acc[j][cc] = b;
    }
    for (int k = 0; k < 64; k += 4) {
        float4 xv[4];
#pragma unroll
        for (int j = 0; j < 4; j++) xv[j] = *(const float4*)&vs[4 * rt + j][k];
#pragma unroll
        for (int kk = 0; kk < 4; kk++) {
            float4 wv0 = *(const float4*)&w1s[k + kk][8 * ct];
            float4 wv1 = *(const float4*)&w1s[k + kk][8 * ct + 4];
#pragma unroll
            for (int j = 0; j < 4; j++) {
                float xx = kk == 0 ? xv[j].x : kk == 1 ? xv[j].y : kk == 2 ? xv[j].z : xv[j].w;
                acc[j][0] = fmaf(xx, wv0.x, acc[j][0]);
                acc[j][1] = fmaf(xx, wv0.y, acc[j][1]);
                acc[j][2] = fmaf(xx, wv0.z, acc[j][2]);
                acc[j][3] = fmaf(xx, wv0.w, acc[j][3]);
                acc[j][4] = fmaf(xx, wv1.x, acc[j][4]);
                acc[j][5] = fmaf(xx, wv1.y, acc[j][5]);
                acc[j][6] = fmaf(xx, wv1.z, acc[j][6]);
                acc[j][7] = fmaf(xx, wv1.w, acc[j][7]);
            }
        }
    }
    float tot = 0.f;
#pragma unroll
    for (int cc = 0; cc < 8; cc++) {
        float w2v = w2[8 * ct + cc];
#pragma unroll
        for (int j = 0; j < 4; j++) tot += fast_tanh(acc[j][cc]) * w2v;
    }
    for (int off = 32; off; off >>= 1) tot += __shfl_xor(tot, off);
    __shared__ float red[4];
    int lane = tid & 63, wid = tid >> 6;
    if (lane == 0) red[wid] = tot;
    __syncthreads();
    if (tid == 0) atomicAdd(&s_acc[combo], red[0] + red[1] + red[2] + red[3]);
}

// ---------------- final product MLP + softmax (beta inline, GEMM-tiled) ----------------
__global__ __launch_bounds__(256) void final_kernel(
    const float* __restrict__ ret, const float* __restrict__ s_acc,
    const float* __restrict__ cw1, const float* __restrict__ cb1, const float* __restrict__ cw2,
    float* __restrict__ outp)
{
    float s0 = s_acc[0] * (1.f / BBB), s1 = s_acc[1] * (1.f / BBB);
    float s2 = s_acc[2] * (1.f / BBB), s3 = s_acc[3] * (1.f / BBB);
    float mu = fmaxf(s0, s1);
    float e0 = __expf(s0 - mu), e1 = __expf(s1 - mu);
    float bu0 = e0 / (e0 + e1), bu1 = e1 / (e0 + e1);
    float mi = fmaxf(s2, s3);
    float f0 = __expf(s2 - mi), f1 = __expf(s3 - mi);
    float bi0 = f0 / (f0 + f1), bi1 = f1 / (f0 + f1);

    __shared__ float xsld[64][68];
    __shared__ float w1s[64][128];
    int tid = threadIdx.x;
    int rowbase = blockIdx.x * 64;
    const float4* r4 = (const float4*)ret;
    for (int li = tid; li < 1024; li += 256) {
        int r = li >> 4, c4 = li & 15;
        float4 a = r4[((long)0 * BBB + rowbase + r) * 16 + c4];
        float4 b = r4[((long)1 * BBB + rowbase + r) * 16 + c4];
        float4 cc = r4[((long)2 * BBB + rowbase + r) * 16 + c4];
        float4 d = r4[((long)3 * BBB + rowbase + r) * 16 + c4];
        float4 xv;
        xv.x = (bu0 * a.x + bu1 * b.x) * (bi0 * cc.x + bi1 * d.x);
        xv.y = (bu0 * a.y + bu1 * b.y) * (bi0 * cc.y + bi1 * d.y);
        xv.z = (bu0 * a.z + bu1 * b.z) * (bi0 * cc.z + bi1 * d.z);
        xv.w = (bu0 * a.w + bu1 * b.w) * (bi0 * cc.w + bi1 * d.w);
        *(float4*)&xsld[r][c4 * 4] = xv;
    }
    const float4* w14 = (const float4*)cw1;
    for (int li = tid; li < 2048; li += 256) {
        float4 v = w14[li];
        *(float4*)&w1s[li >> 5][(li & 31) * 4] = v;
    }
    __syncthreads();
    int ct = tid & 15, rt = tid >> 4;
    float acc[4][8];
#pragma unroll
    for (int cc = 0; cc < 8; cc++) {
        float b = cb1[8 * ct + cc];
#pragma unroll
        for (int j = 0; j < 4; j++) acc[j][cc] = b;
    }
    for (int k = 0; k < 64; k += 4) {
        float4 xv[4];
#pragma unroll
        for (int j = 0; j < 4; j++) xv[j] = *(const float4*)&xsld[4 * rt + j][k];
#pragma unroll
        for (int kk = 0; kk < 4; kk++) {
            float4 wv0 = *(const float4*)&w1s[k + kk][8 * ct];
            float4 wv1 = *(const float4*)&w1s[k + kk][8 * ct + 4];
#pragma unroll
            for (int j = 0; j < 4; j++) {
                float xx = kk == 0 ? xv[j].x : kk == 1 ? xv[j].y : kk == 2 ? xv[j].z : xv[j].w;
                acc[j][0] = fmaf(xx, wv0.x, acc[j][0]);
                acc[j][1] = fmaf(xx, wv0.y, acc[j][1]);
                acc[j][2] = fmaf(xx, wv0.z, acc[j][2]);
                acc[j][3] = fmaf(xx, wv0.w, acc[j][3]);
                acc[j][4] = fmaf(xx, wv1.x, acc[j][4]);
                acc[j][5] = fmaf(xx, wv1.y, acc[j][5]);
                acc[j][6] = fmaf(xx, wv1.z, acc[j][6]);
                acc[j][7] = fmaf(xx, wv1.w, acc[j][7]);
            }
        }
    }
    float pp0[4], pp1[4];
#pragma unroll
    for (int j = 0; j < 4; j++) { pp0[j] = 0.f; pp1[j] = 0.f; }
#pragma unroll
    for (int cc = 0; cc < 8; cc++) {
        int col = 8 * ct + cc;
        float c0 = cw2[col * 2], c1 = cw2[col * 2 + 1];
#pragma unroll
        for (int j = 0; j < 4; j++) {
            float h = fmaxf(acc[j][cc], 0.f);
            pp0[j] = fmaf(h, c0, pp0[j]);
            pp1[j] = fmaf(h, c1, pp1[j]);
        }
    }
    __syncthreads();
    float2* red = (float2*)xsld;
#pragma unroll
    for (int j = 0; j < 4; j++)
        red[(4 * rt + j) * 16 + ct] = make_float2(pp0[j], pp1[j]);
    __syncthreads();
    if (tid < 64) {
        float q0 = 0.f, q1 = 0.f;
        for (int i = 0; i < 16; i++) {
            float2 e = red[tid * 16 + i];
            q0 += e.x; q1 += e.y;
        }
        float mx = fmaxf(q0, q1);
        float a0 = __expf(q0 - mx), a1 = __expf(q1 - mx);
        float dn = a0 + a1;
        outp[(rowbase + tid) * 2] = a0 / dn;
        outp[(rowbase + tid) * 2 + 1] = a1 / dn;
    }
}

extern "C" void kernel_launch(void* const* d_in, const int* in_sizes, int n_in,
                              void* d_out, int out_size, void* d_ws, size_t ws_size,
                              hipStream_t stream)
{
    const float* feats0 = (const float*)d_in[0];
    const float* feats1 = (const float*)d_in[1];
    const float* t0_pw = (const float*)d_in[2];
    const float* t0_pb = (const float*)d_in[3];
    const float* t0_w2 = (const float*)d_in[4];
    const float* t0_b2 = (const float*)d_in[5];
    const float* t0_g  = (const float*)d_in[6];
    const float* t0_be = (const float*)d_in[7];
    const float* t1_pw = (const float*)d_in[8];
    const float* t1_pb = (const float*)d_in[9];
    const float* t1_w2 = (const float*)d_in[10];
    const float* t1_b2 = (const float*)d_in[11];
    const float* t1_g  = (const float*)d_in[12];
    const float* t1_be = (const float*)d_in[13];
    const float* r_vec = (const float*)d_in[14];
    const float* attn_user = (const float*)d_in[15];
    const float* attn_item = (const float*)d_in[16];
    const float* su_w1 = (const float*)d_in[17];
    const float* su_b1 = (const float*)d_in[18];
    const float* su_w2 = (const float*)d_in[19];
    const float* si_w1 = (const float*)d_in[20];
    const float* si_b1 = (const float*)d_in[21];
    const float* si_w2 = (const float*)d_in[22];
    const float* cw1 = (const float*)d_in[23];
    const float* cb1 = (const float*)d_in[24];
    const float* cw2 = (const float*)d_in[25];
    const int* idx0 = (const int*)d_in[26];
    const int* idx1 = (const int*)d_in[27];
    const int* emi_user = (const int*)d_in[28];
    const int* tgt_user = (const int*)d_in[29];
    const int* emi_item = (const int*)d_in[30];
    const int* tgt_item = (const int*)d_in[31];
    float* outp = (float*)d_out;

    // workspace layout (256B aligned)
    char* ws = (char*)d_ws;
    __hip_bfloat16* feat = (__hip_bfloat16*)(ws + 0);   // 5,120,000
    int*     cnt    = (int*)(ws + 5120000);             // 131,072
    int*     cur    = (int*)(ws + 5251072);             // 131,072 (contiguous with cnt for one memset)
    int*     cur32  = (int*)(ws + 5382144);             // 512
    int*     offs   = (int*)(ws + 5382656);             // 131,088 -> pad 131,328
    float*   s_acc  = (float*)(ws + 5513984);           // 256
    ushort4* binbuf = (ushort4*)(ws + 5514240);         // 6,400,000
    ushort4* nodes  = (ushort4*)(ws + 11914240);        // 6,400,000
    float*   ret_buf= (float*)(ws + 18314240);          // 8,388,608
    __bf16*  wprep  = (__bf16*)(ws + 26702848);         // 262,144  (end ~27.0 MB)
    // w2prep (32KB) aliases the start of binbuf: tower reads it BEFORE binA writes binbuf
    // (stream-ordered: prep_w -> tower -> hist/scan -> binA).
    __bf16*  w2prep = (__bf16*)(ws + 5514240);

    prep_w<<<dim3(2, 8), 256, 0, stream>>>(t0_pw, t1_pw, t0_w2, t1_w2, wprep, w2prep);

    tower_kernel<<<dim3(NN0 / 16, 2), 64, 0, stream>>>(
        feats0, feats1, wprep, w2prep, t0_pb, t1_pb,
        t0_b2, t1_b2, t0_g, t1_g, t0_be, t1_be, idx0, idx1, feat);

    hipMemsetAsync(cnt, 0, 2 * 4 * BBB * sizeof(int), stream);
    hist_kernel<<<dim3((EEE + 255) / 256, 4), 256, 0, stream>>>(tgt_user, tgt_item, cnt);
    scan_kernel<<<4, 256, 0, stream>>>(cnt, offs, cur32, s_acc);
    binA_kernel<<<dim3((EEE + CHUNK - 1) / CHUNK, 4), 256, 0, stream>>>(
        tgt_user, tgt_item, emi_user, emi_item, cur32, binbuf);
    binB_kernel<<<dim3(64, 4), 256, 0, stream>>>(offs, cur, binbuf, nodes);

    flash_mp<<<dim3(BBB / 4, 4), 256, 0, stream>>>(feat, nodes, offs, r_vec,
                                                   attn_user, attn_item, ret_buf);

    sem_kernel<<<dim3(BBB / 64, 4), 256, 0, stream>>>(ret_buf, su_w1, su_b1, su_w2,
                                                      si_w1, si_b1, si_w2, s_acc);
    final_kernel<<<BBB / 64, 256, 0, stream>>>(ret_buf, s_acc, cw1, cb1, cw2, outp);
}

// Round 3
// 332.579 us; speedup vs baseline: 1.2743x; 1.0684x over previous
//
#include <hip/hip_runtime.h>
#include <hip/hip_bf16.h>
#include <math.h>

// MAGNN link prediction forward — fp32 compute; feat table stored bf16.
// Tower: barrier-free per-wave MFMA GEMM (split-bf16 hi/lo, 3 MFMAs ~ fp32 accuracy).
// Flash: deferred-rotation packed-f32 online softmax.
#define NN0 20000
#define NN1 20000
#define NTOT 40000
#define FF0 512
#define HIDD 64
#define EEE 200000
#define BBB 8192
#define AVV 128
#define CHH 128

typedef __bf16 bf16x8 __attribute__((ext_vector_type(8)));
typedef __bf16 bf16x4 __attribute__((ext_vector_type(4)));
typedef float f32x4 __attribute__((ext_vector_type(4)));
typedef float f32x2 __attribute__((ext_vector_type(2)));

__device__ __forceinline__ float fast_tanh(float x) {
    float e2 = __expf(2.f * x);
    return 1.f - 2.f / (e2 + 1.f);
}

__device__ __forceinline__ f32x2 bf2_to_f32x2(unsigned int c) {
    f32x2 r;
    r.x = __uint_as_float(c << 16);
    r.y = __uint_as_float(c & 0xffff0000u);
    return r;
}

// ---------------- fused: weight prep (blocks 0..15) + target histogram (rest) ----------------
// prep: hi/lo bf16 split into exact B-fragment order.
// GEMM1 (pw [512][64]): fragment element (ks, nt, lane, j) holds w[k][n] with
//   k = ks*32 + (lane>>4)*8 + j, n = nt*16 + (lane&15).
// hi at [((ks*4+nt)*64 + lane)*8 + j], lo at +32768 (per tower: 65536 bf16 = 128KB).
// GEMM2 (w2 [64][64]): same formula, ks in 0..1; per tower 8192 bf16 = 16KB.
__global__ __launch_bounds__(256) void prep_hist(
    const float* __restrict__ pw0, const float* __restrict__ pw1,
    const float* __restrict__ w20, const float* __restrict__ w21,
    __bf16* __restrict__ wprep, __bf16* __restrict__ w2prep,
    const int* __restrict__ tgt_user, const int* __restrict__ tgt_item,
    int* __restrict__ cnt)
{
    int bx = blockIdx.x;
    if (bx < 16) {
        int tw = bx & 1, seg = bx >> 1;
        const float* w = tw ? pw1 : pw0;
        __bf16* base = wprep + tw * 65536;
        for (int idx = seg * 4096 + threadIdx.x; idx < (seg + 1) * 4096; idx += 256) {
            int k = idx >> 6, n = idx & 63;
            float v = w[idx];
            __bf16 hi = (__bf16)v;
            __bf16 lo = (__bf16)(v - (float)hi);
            int ks = k >> 5, kb = (k >> 3) & 3, j = k & 7;
            int nt = n >> 4, fr = n & 15;
            int lane = kb * 16 + fr;
            int off = ((ks * 4 + nt) * 64 + lane) * 8 + j;
            base[off] = hi;
            base[32768 + off] = lo;
        }
        const float* w2 = tw ? w21 : w20;
        __bf16* base2 = w2prep + tw * 8192;
        for (int idx = seg * 512 + threadIdx.x; idx < (seg + 1) * 512; idx += 256) {
            int k = idx >> 6, n = idx & 63;
            float v = w2[idx];
            __bf16 hi = (__bf16)v;
            __bf16 lo = (__bf16)(v - (float)hi);
            int ks = k >> 5, kb = (k >> 3) & 3, j = k & 7;
            int nt = n >> 4, fr = n & 15;
            int lane = kb * 16 + fr;
            int off = ((ks * 4 + nt) * 64 + lane) * 8 + j;
            base2[off] = hi;
            base2[4096 + off] = lo;
        }
    } else {
        int flat = bx - 16;                    // 0..3127
        int combo = flat & 3, blk = flat >> 2; // blk 0..781
        const int* tgt = (combo < 2 ? tgt_user : tgt_item) + (long)(combo & 1) * EEE;
        int i = blk * 256 + threadIdx.x;
        if (i < EEE) atomicAdd(&cnt[combo * BBB + tgt[i]], 1);
    }
}

// ---------------- scan: per-combo exclusive prefix over 8192 counters ----------------
__global__ __launch_bounds__(256) void scan_kernel(const int* __restrict__ cnt, int* __restrict__ offs,
                                                   int* __restrict__ cur32, float* __restrict__ s_acc)
{
    int pth = blockIdx.x;
    if (pth == 0 && threadIdx.x < 4) s_acc[threadIdx.x] = 0.f;
    const int* c = cnt + pth * BBB;
    int* o = offs + pth * (BBB + 1);
    __shared__ int part[256];
    int tid = threadIdx.x;
    int base = tid * 32;
    int local[32];
    int sum = 0;
    for (int j = 0; j < 32; j++) { local[j] = sum; sum += c[base + j]; }
    part[tid] = sum;
    __syncthreads();
    for (int d = 1; d < 256; d <<= 1) {
        int v = (tid >= d) ? part[tid - d] : 0;
        __syncthreads();
        part[tid] += v;
        __syncthreads();
    }
    int pre = (tid == 0) ? 0 : part[tid - 1];
    for (int j = 0; j < 32; j++) {
        int val = pre + local[j];
        o[base + j] = val;
        if (((base + j) & 255) == 0) cur32[pth * 32 + ((base + j) >> 8)] = val;
    }
    if (tid == 255) o[BBB] = pre + sum;
}

// ---------------- fused: tower MFMA (blocks 0..2499) + binA coarse binning (rest) ----------------
// Tower: 1 wave per block; wave owns 16 rows x 64 cols, full K=512.
// A fragments direct from global fp32 x (convert in-register, hi/lo split).
// B fragments direct from prepacked global image (L2-resident). No barriers in K-loop.
// binA: 64-thread variant, 512 entries/block, LDS-sorted coarse bucket scatter.
#define CHUNKF 512
__global__ __launch_bounds__(64) void tower_binA(
    const float* __restrict__ x0, const float* __restrict__ x1,
    const __bf16* __restrict__ wprep, const __bf16* __restrict__ w2prep,
    const float* __restrict__ pb0, const float* __restrict__ pb1,
    const float* __restrict__ b20, const float* __restrict__ b21,
    const float* __restrict__ g0, const float* __restrict__ g1,
    const float* __restrict__ be0, const float* __restrict__ be1,
    const int* __restrict__ idxa, const int* __restrict__ idxb,
    __hip_bfloat16* __restrict__ feat,
    const int* __restrict__ tgt_user, const int* __restrict__ tgt_item,
    const int* __restrict__ emi_user, const int* __restrict__ emi_item,
    int* __restrict__ cur32, ushort4* __restrict__ binbuf)
{
    __shared__ __align__(16) char pool[4624];
    int bx = blockIdx.x;
    if (bx < 2500) {
        int tile = bx >> 1, tw = bx & 1;
        const float* x  = tw ? x1 : x0;
        const float* pb = tw ? pb1 : pb0;
        const float* b2 = tw ? b21 : b20;
        const float* g  = tw ? g1 : g0;
        const float* be = tw ? be1 : be0;
        const int* idx  = tw ? idxb : idxa;
        float (*hs)[68] = (float(*)[68])pool;

        int l = threadIdx.x;
        int fr = l & 15, kb = l >> 4;
        int row0 = tile * 16;
        const float* xp = x + (long)(row0 + fr) * FF0 + kb * 8;
        const __bf16* bp = wprep + tw * 65536;

        f32x4 acc[4];
#pragma unroll
        for (int nt = 0; nt < 4; nt++) acc[nt] = (f32x4){0.f, 0.f, 0.f, 0.f};

        float4 a0c, a1c, a0n, a1n;
        bf16x8 bhc[4], blc[4], bhn[4], bln[4];

        a0c = *(const float4*)xp;
        a1c = *(const float4*)(xp + 4);
#pragma unroll
        for (int nt = 0; nt < 4; nt++) {
            bhc[nt] = *(const bf16x8*)(bp + (nt * 64 + l) * 8);
            blc[nt] = *(const bf16x8*)(bp + 32768 + (nt * 64 + l) * 8);
        }

#pragma unroll 2
        for (int ks = 0; ks < 16; ks++) {
            if (ks + 1 < 16) {
                a0n = *(const float4*)(xp + (ks + 1) * 32);
                a1n = *(const float4*)(xp + (ks + 1) * 32 + 4);
#pragma unroll
                for (int nt = 0; nt < 4; nt++) {
                    bhn[nt] = *(const bf16x8*)(bp + (((ks + 1) * 4 + nt) * 64 + l) * 8);
                    bln[nt] = *(const bf16x8*)(bp + 32768 + (((ks + 1) * 4 + nt) * 64 + l) * 8);
                }
            }
            float av[8] = {a0c.x, a0c.y, a0c.z, a0c.w, a1c.x, a1c.y, a1c.z, a1c.w};
            bf16x8 ah, al;
#pragma unroll
            for (int j = 0; j < 8; j++) {
                __bf16 h = (__bf16)av[j];
                ah[j] = h;
                al[j] = (__bf16)(av[j] - (float)h);
            }
#pragma unroll
            for (int nt = 0; nt < 4; nt++) {
                acc[nt] = __builtin_amdgcn_mfma_f32_16x16x32_bf16(ah, bhc[nt], acc[nt], 0, 0, 0);
                acc[nt] = __builtin_amdgcn_mfma_f32_16x16x32_bf16(al, bhc[nt], acc[nt], 0, 0, 0);
                acc[nt] = __builtin_amdgcn_mfma_f32_16x16x32_bf16(ah, blc[nt], acc[nt], 0, 0, 0);
            }
            a0c = a0n; a1c = a1n;
#pragma unroll
            for (int nt = 0; nt < 4; nt++) { bhc[nt] = bhn[nt]; blc[nt] = bln[nt]; }
        }

        // epilogue 1: z = acc + pb; h = gelu(z) -> hs; acc2 = z + b2
        float pbv[4], b2v[4];
#pragma unroll
        for (int nt = 0; nt < 4; nt++) { pbv[nt] = pb[nt * 16 + fr]; b2v[nt] = b2[nt * 16 + fr]; }
        f32x4 acc2[4];
#pragma unroll
        for (int nt = 0; nt < 4; nt++) {
#pragma unroll
            for (int j = 0; j < 4; j++) {
                float z = acc[nt][j] + pbv[nt];
                float h = 0.5f * z * (1.f + erff(z * 0.70710678118654752f));
                hs[kb * 4 + j][nt * 16 + fr] = h;
                acc2[nt][j] = z + b2v[nt];
            }
        }
        __syncthreads();

        // GEMM2 (MFMA): y = h@w2 + b2 + z
        const __bf16* w2p = w2prep + tw * 8192;
#pragma unroll
        for (int ks = 0; ks < 2; ks++) {
            float4 h0 = *(const float4*)&hs[fr][ks * 32 + kb * 8];
            float4 h1 = *(const float4*)&hs[fr][ks * 32 + kb * 8 + 4];
            float hv[8] = {h0.x, h0.y, h0.z, h0.w, h1.x, h1.y, h1.z, h1.w};
            bf16x8 ah, al;
#pragma unroll
            for (int j = 0; j < 8; j++) {
                __bf16 h = (__bf16)hv[j];
                ah[j] = h;
                al[j] = (__bf16)(hv[j] - (float)h);
            }
#pragma unroll
            for (int nt = 0; nt < 4; nt++) {
                bf16x8 bh2 = *(const bf16x8*)(w2p + ((ks * 4 + nt) * 64 + l) * 8);
                bf16x8 bl2 = *(const bf16x8*)(w2p + 4096 + ((ks * 4 + nt) * 64 + l) * 8);
                acc2[nt] = __builtin_amdgcn_mfma_f32_16x16x32_bf16(ah, bh2, acc2[nt], 0, 0, 0);
                acc2[nt] = __builtin_amdgcn_mfma_f32_16x16x32_bf16(al, bh2, acc2[nt], 0, 0, 0);
                acc2[nt] = __builtin_amdgcn_mfma_f32_16x16x32_bf16(ah, bl2, acc2[nt], 0, 0, 0);
            }
        }
        __syncthreads();

        // LayerNorm in-register
        float gv[4], bev[4];
#pragma unroll
        for (int nt = 0; nt < 4; nt++) { gv[nt] = g[nt * 16 + fr]; bev[nt] = be[nt * 16 + fr]; }
#pragma unroll
        for (int j = 0; j < 4; j++) {
            float p = acc2[0][j] + acc2[1][j] + acc2[2][j] + acc2[3][j];
            p += __shfl_xor(p, 1); p += __shfl_xor(p, 2);
            p += __shfl_xor(p, 4); p += __shfl_xor(p, 8);
            float mu = p * (1.f / 64.f);
            float d[4], vs = 0.f;
#pragma unroll
            for (int nt = 0; nt < 4; nt++) { d[nt] = acc2[nt][j] - mu; vs += d[nt] * d[nt]; }
            vs += __shfl_xor(vs, 1); vs += __shfl_xor(vs, 2);
            vs += __shfl_xor(vs, 4); vs += __shfl_xor(vs, 8);
            float is = 1.f / sqrtf(vs * (1.f / 64.f) + 1e-5f);
#pragma unroll
            for (int nt = 0; nt < 4; nt++)
                hs[kb * 4 + j][nt * 16 + fr] = d[nt] * is * gv[nt] + bev[nt];
        }
        __syncthreads();
#pragma unroll 4
        for (int r = 0; r < 16; r++) {
            int grow = row0 + r;
            feat[(long)idx[grow] * HIDD + l] = __float2bfloat16(hs[r][l]);
        }
    } else {
        int flat = bx - 2500;
        int combo = flat & 3;
        int base = (flat >> 2) * CHUNKF;
        const int* tgt = (combo < 2 ? tgt_user : tgt_item) + (long)(combo & 1) * EEE;
        const int* emi = (combo < 2 ? emi_user : emi_item) + (long)(combo & 1) * EEE * 3;
        ushort4* sbuf = (ushort4*)pool;
        int* lcnt  = (int*)(pool + 4096);
        int* lofs  = lcnt + 32;
        int* gbase = lofs + 33;
        int* lcur  = gbase + 32;
        int tid = threadIdx.x;
        if (tid < 32) { lcnt[tid] = 0; lcur[tid] = 0; }
        __syncthreads();
        ushort4 ent[8]; int bk[8];
#pragma unroll
        for (int ps = 0; ps < 8; ps++) {
            int i = base + ps * 64 + tid;
            if (i < EEE) {
                int t = tgt[i];
                ent[ps] = make_ushort4((unsigned short)emi[3 * i], (unsigned short)emi[3 * i + 1],
                                       (unsigned short)emi[3 * i + 2], (unsigned short)t);
                bk[ps] = t >> 8;
                atomicAdd(&lcnt[bk[ps]], 1);
            } else bk[ps] = -1;
        }
        __syncthreads();
        if (tid == 0) {
            int run = 0;
            for (int k = 0; k < 32; k++) { lofs[k] = run; run += lcnt[k]; }
            lofs[32] = run;
        }
        __syncthreads();
        if (tid < 32) gbase[tid] = atomicAdd(&cur32[combo * 32 + tid], lcnt[tid]);
        __syncthreads();
#pragma unroll
        for (int ps = 0; ps < 8; ps++) {
            if (bk[ps] >= 0) {
                int pos = lofs[bk[ps]] + atomicAdd(&lcur[bk[ps]], 1);
                sbuf[pos] = ent[ps];
            }
        }
        __syncthreads();
        int total = lofs[32];
        ushort4* dst = binbuf + (long)combo * EEE;
        for (int j = tid; j < total; j += 64) {
            ushort4 e = sbuf[j];
            int k = e.w >> 8;
            dst[gbase[k] + (j - lofs[k])] = e;
        }
    }
}

// pass B: within each coarse bucket (contiguous ~50KB window), place entries at exact CSR position
__global__ __launch_bounds__(256) void binB_kernel(
    const int* __restrict__ offs, int* __restrict__ cur,
    const ushort4* __restrict__ binbuf, ushort4* __restrict__ nodes)
{
    int combo = blockIdx.y;
    int k = blockIdx.x >> 1, part = blockIdx.x & 1;
    const int* of = offs + combo * (BBB + 1);
    int rbeg = of[k << 8], rend = of[(k + 1) << 8];
    const ushort4* src = binbuf + (long)combo * EEE;
    ushort4* dst = nodes + (long)combo * EEE;
    int* cu = cur + combo * BBB;
    for (int j = rbeg + part * 256 + threadIdx.x; j < rend; j += 512) {
        ushort4 e = src[j];
        int t = e.w;
        int pos = of[t] + atomicAdd(&cu[t], 1);
        dst[pos] = e;
    }
}

// ---------------- flash metapath: deferred rotation + packed f32 + online softmax + ELU ----------------
// hidden = (u0 + u2 + R*u1)/3. Rotation is linear -> accumulate A02=Σw(u0+u2), A1=Σw*u1,
// apply R once at the end. Logit folds R into attn: e = (u0+u2)·(a/3) + u1·(Rᵀa/3).
__global__ __launch_bounds__(256) void flash_mp(
    const __hip_bfloat16* __restrict__ feat, const ushort4* __restrict__ nodes,
    const int* __restrict__ offs, const float* __restrict__ r_vec,
    const float* __restrict__ attn_user, const float* __restrict__ attn_item,
    float* __restrict__ ret)
{
    int combo = blockIdx.y;
    int wid = threadIdx.x >> 6, lane = threadIdx.x & 63;
    int half = lane >> 5, p = lane & 31;
    int side = combo >> 1;
    const float* attn = (side == 0 ? attn_user : attn_item) + (combo & 1) * 64;
    const unsigned int* f2 = (const unsigned int*)feat;
    float2 rb = ((const float2*)r_vec)[p];
    float invn = 1.f / sqrtf(rb.x * rb.x + rb.y * rb.y);
    float rvx = rb.x * invn, rvy = rb.y * invn;
    if (side == 0) rvy = -rvy;
    float aRe = attn[2 * p], aIm = attn[2 * p + 1];
    f32x2 av  = { aRe * (1.f / 3.f), aIm * (1.f / 3.f) };
    f32x2 apv = { (rvx * aRe + rvy * aIm) * (1.f / 3.f),
                  (rvx * aIm - rvy * aRe) * (1.f / 3.f) };
    int t = blockIdx.x * 4 + wid;
    const int* of = offs + combo * (BBB + 1);
    int beg = of[t], end = of[t + 1];
    int n = end - beg;
    const ushort4* nd = nodes + (long)combo * EEE;

    float m = -3.4e38f, s = 0.f;
    f32x2 A02 = {0.f, 0.f}, A1 = {0.f, 0.f};

    unsigned int c0[4], c1[4], c2[4];
    ushort4 nq[4];
    if (n > 0) {
#pragma unroll
        for (int q = 0; q < 4; q++) {
            ushort4 a = nd[min(beg + 2 * q + half, EEE - 1)];
            c0[q] = f2[(int)a.x * 32 + p];
            c1[q] = f2[(int)a.y * 32 + p];
            c2[q] = f2[(int)a.z * 32 + p];
        }
#pragma unroll
        for (int q = 0; q < 4; q++)
            nq[q] = nd[min(beg + 8 + 2 * q + half, EEE - 1)];
    }
    for (int it = 0; it < n; it += 8) {
        f32x2 u1[4], v02[4];
        float e[4];
#pragma unroll
        for (int q = 0; q < 4; q++) {
            f32x2 u0 = bf2_to_f32x2(c0[q]);
            u1[q]    = bf2_to_f32x2(c1[q]);
            f32x2 u2 = bf2_to_f32x2(c2[q]);
            v02[q] = u0 + u2;
        }
        if (it + 8 < n) {
#pragma unroll
            for (int q = 0; q < 4; q++) {
                c0[q] = f2[(int)nq[q].x * 32 + p];
                c1[q] = f2[(int)nq[q].y * 32 + p];
                c2[q] = f2[(int)nq[q].z * 32 + p];
            }
#pragma unroll
            for (int q = 0; q < 4; q++)
                nq[q] = nd[min(beg + it + 16 + 2 * q + half, EEE - 1)];
        }
#pragma unroll
        for (int q = 0; q < 4; q++) {
            f32x2 tt = v02[q] * av + u1[q] * apv;
            float pa = tt.x + tt.y;
            pa += __shfl_xor(pa, 1);
            pa += __shfl_xor(pa, 2);
            e[q] = fmaxf(pa, 0.01f * pa);        // leaky_relu
        }
        if (it + 8 > n) {                        // tail chunk only (wave-uniform)
#pragma unroll
            for (int q = 0; q < 4; q++)
                if (it + 2 * q + half >= n) e[q] = -3.4e38f;
        }
        float mx = fmaxf(fmaxf(e[0], e[1]), fmaxf(e[2], e[3]));
        float mn = fmaxf(m, fmaxf(mx, __shfl_xor(mx, 32)));
        float alpha = __expf(m - mn);
        s *= alpha; A02 *= alpha; A1 *= alpha;
        float wl = 0.f;
#pragma unroll
        for (int q = 0; q < 4; q++) {
            float w = __expf(e[q] - mn);
            wl += w;
            A02 += v02[q] * w;
            A1  += u1[q] * w;
        }
        s += wl + __shfl_xor(wl, 32);
        m = mn;
    }
    float Sx = A02.x + __shfl_xor(A02.x, 32);
    float Sy = A02.y + __shfl_xor(A02.y, 32);
    float Tx = A1.x + __shfl_xor(A1.x, 32);
    float Ty = A1.y + __shfl_xor(A1.y, 32);
    float inv = (1.f / 3.f) / (s + 1e-9f);
    float vx = (Sx + rvx * Tx - rvy * Ty) * inv;
    float vy = (Sy + rvx * Ty + rvy * Tx) * inv;
    vx = vx > 0.f ? vx : __expf(vx) - 1.f;       // ELU
    vy = vy > 0.f ? vy : __expf(vy) - 1.f;
    if (half == 0)
        ((float2*)ret)[((long)combo * BBB + t) * 32 + p] = make_float2(vx, vy);
}

// ---------------- semantic score GEMM: s_acc[combo] = sum_b tanh(ret_b @ w1 + b1) @ w2 ----------------
__global__ __launch_bounds__(256) void sem_kernel(
    const float* __restrict__ ret,
    const float* __restrict__ su_w1, const float* __restrict__ su_b1, const float* __restrict__ su_w2,
    const float* __restrict__ si_w1, const float* __restrict__ si_b1, const float* __restrict__ si_w2,
    float* __restrict__ s_acc)
{
    int combo = blockIdx.y;
    int side = combo >> 1;
    const float* w1 = side ? si_w1 : su_w1;
    const float* b1 = side ? si_b1 : su_b1;
    const float* w2 = side ? si_w2 : su_w2;
    __shared__ float vs[64][68];
    __shared__ float w1s[64][128];
    int tid = threadIdx.x;
    int rowbase = blockIdx.x * 64;
    const float4* r4 = (const float4*)ret;
    for (int li = tid; li < 1024; li += 256) {
        int r = li >> 4, c4 = li & 15;
        float4 v = r4[((long)combo * BBB + rowbase + r) * 16 + c4];
        *(float4*)&vs[r][c4 * 4] = v;
    }
    const float4* w14 = (const float4*)w1;
    for (int li = tid; li < 2048; li += 256) {
        float4 v = w14[li];
        *(float4*)&w1s[li >> 5][(li & 31) * 4] = v;
    }
    __syncthreads();
    int ct = tid & 15, rt = tid >> 4;
    float acc[4][8];
#pragma unroll
    for (int cc = 0; cc < 8; cc++) {
        float b = b1[8 * ct + cc];
#pragma unroll
        for (int j = 0; j < 4; j++) acc[j][cc] = b;
    }
    for (int k = 0; k < 64; k += 4) {
        float4 xv[4];
#pragma unroll
        for (int j = 0; j < 4; j++) xv[j] = *(const float4*)&vs[4 * rt + j][k];
#pragma unroll
        for (int kk = 0; kk < 4; kk++) {
            float4 wv0 = *(const float4*)&w1s[k + kk][8 * ct];
            float4 wv1 = *(const float4*)&w1s[k + kk][8 * ct + 4];
#pragma unroll
            for (int j = 0; j < 4; j++) {
                float xx = kk == 0 ? xv[j].x : kk == 1 ? xv[j].y : kk == 2 ? xv[j].z : xv[j].w;
                acc[j][0] = fmaf(xx, wv0.x, acc[j][0]);
                acc[j][1] = fmaf(xx, wv0.y, acc[j][1]);
                acc[j][2] = fmaf(xx, wv0.z, acc[j][2]);
                acc[j][3] = fmaf(xx, wv0.w, acc[j][3]);
                acc[j][4] = fmaf(xx, wv1.x, acc[j][4]);
                acc[j][5] = fmaf(xx, wv1.y, acc[j][5]);
                acc[j][6] = fmaf(xx, wv1.z, acc[j][6]);
                acc[j][7] = fmaf(xx, wv1.w, acc[j][7]);
            }
        }
    }
    float tot = 0.f;
#pragma unroll
    for (int cc = 0; cc < 8; cc++) {
        float w2v = w2[8 * ct + cc];
#pragma unroll
        for (int j = 0; j < 4; j++) tot += fast_tanh(acc[j][cc]) * w2v;
    }
    for (int off = 32; off; off >>= 1) tot += __shfl_xor(tot, off);
    __shared__ float red[4];
    int lane = tid & 63, wid = tid >> 6;
    if (lane == 0) red[wid] = tot;
    __syncthreads();
    if (tid == 0) atomicAdd(&s_acc[combo], red[0] + red[1] + red[2] + red[3]);
}

// ---------------- final product MLP + softmax (beta inline, GEMM-tiled) ----------------
__global__ __launch_bounds__(256) void final_kernel(
    const float* __restrict__ ret, const float* __restrict__ s_acc,
    const float* __restrict__ cw1, const float* __restrict__ cb1, const float* __restrict__ cw2,
    float* __restrict__ outp)
{
    float s0 = s_acc[0] * (1.f / BBB), s1 = s_acc[1] * (1.f / BBB);
    float s2 = s_acc[2] * (1.f / BBB), s3 = s_acc[3] * (1.f / BBB);
    float mu = fmaxf(s0, s1);
    float e0 = __expf(s0 - mu), e1 = __expf(s1 - mu);
    float bu0 = e0 / (e0 + e1), bu1 = e1 / (e0 + e1);
    float mi = fmaxf(s2, s3);
    float f0 = __expf(s2 - mi), f1 = __expf(s3 - mi);
    float bi0 = f0 / (f0 + f1), bi1 = f1 / (f0 + f1);

    __shared__ float xsld[64][68];
    __shared__ float w1s[64][128];
    int tid = threadIdx.x;
    int rowbase = blockIdx.x * 64;
    const float4* r4 = (const float4*)ret;
    for (int li = tid; li < 1024; li += 256) {
        int r = li >> 4, c4 = li & 15;
        float4 a = r4[((long)0 * BBB + rowbase + r) * 16 + c4];
        float4 b = r4[((long)1 * BBB + rowbase + r) * 16 + c4];
        float4 cc = r4[((long)2 * BBB + rowbase + r) * 16 + c4];
        float4 d = r4[((long)3 * BBB + rowbase + r) * 16 + c4];
        float4 xv;
        xv.x = (bu0 * a.x + bu1 * b.x) * (bi0 * cc.x + bi1 * d.x);
        xv.y = (bu0 * a.y + bu1 * b.y) * (bi0 * cc.y + bi1 * d.y);
        xv.z = (bu0 * a.z + bu1 * b.z) * (bi0 * cc.z + bi1 * d.z);
        xv.w = (bu0 * a.w + bu1 * b.w) * (bi0 * cc.w + bi1 * d.w);
        *(float4*)&xsld[r][c4 * 4] = xv;
    }
    const float4* w14 = (const float4*)cw1;
    for (int li = tid; li < 2048; li += 256) {
        float4 v = w14[li];
        *(float4*)&w1s[li >> 5][(li & 31) * 4] = v;
    }
    __syncthreads();
    int ct = tid & 15, rt = tid >> 4;
    float acc[4][8];
#pragma unroll
    for (int cc = 0; cc < 8; cc++) {
        float b = cb1[8 * ct + cc];
#pragma unroll
        for (int j = 0; j < 4; j++) acc[j][cc] = b;
    }
    for (int k = 0; k < 64; k += 4) {
        float4 xv[4];
#pragma unroll
        for (int j = 0; j < 4; j++) xv[j] = *(const float4*)&xsld[4 * rt + j][k];
#pragma unroll
        for (int kk = 0; kk < 4; kk++) {
            float4 wv0 = *(const float4*)&w1s[k + kk][8 * ct];
            float4 wv1 = *(const float4*)&w1s[k + kk][8 * ct + 4];
#pragma unroll
            for (int j = 0; j < 4; j++) {
                float xx = kk == 0 ? xv[j].x : kk == 1 ? xv[j].y : kk == 2 ? xv[j].z : xv[j].w;
                acc[j][0] = fmaf(xx, wv0.x, acc[j][0]);
                acc[j][1] = fmaf(xx, wv0.y, acc[j][1]);
                acc[j][2] = fmaf(xx, wv0.z, acc[j][2]);
                acc[j][3] = fmaf(xx, wv0.w, acc[j][3]);
                acc[j][4] = fmaf(xx, wv1.x, acc[j][4]);
                acc[j][5] = fmaf(xx, wv1.y, acc[j][5]);
                acc[j][6] = fmaf(xx, wv1.z, acc[j][6]);
                acc[j][7] = fmaf(xx, wv1.w, acc[j][7]);
            }
        }
    }
    float pp0[4], pp1[4];
#pragma unroll
    for (int j = 0; j < 4; j++) { pp0[j] = 0.f; pp1[j] = 0.f; }
#pragma unroll
    for (int cc = 0; cc < 8; cc++) {
        int col = 8 * ct + cc;
        float c0 = cw2[col * 2], c1 = cw2[col * 2 + 1];
#pragma unroll
        for (int j = 0; j < 4; j++) {
            float h = fmaxf(acc[j][cc], 0.f);
            pp0[j] = fmaf(h, c0, pp0[j]);
            pp1[j] = fmaf(h, c1, pp1[j]);
        }
    }
    __syncthreads();
    float2* red = (float2*)xsld;
#pragma unroll
    for (int j = 0; j < 4; j++)
        red[(4 * rt + j) * 16 + ct] = make_float2(pp0[j], pp1[j]);
    __syncthreads();
    if (tid < 64) {
        float q0 = 0.f, q1 = 0.f;
        for (int i = 0; i < 16; i++) {
            float2 e = red[tid * 16 + i];
            q0 += e.x; q1 += e.y;
        }
        float mx = fmaxf(q0, q1);
        float a0 = __expf(q0 - mx), a1 = __expf(q1 - mx);
        float dn = a0 + a1;
        outp[(rowbase + tid) * 2] = a0 / dn;
        outp[(rowbase + tid) * 2 + 1] = a1 / dn;
    }
}

extern "C" void kernel_launch(void* const* d_in, const int* in_sizes, int n_in,
                              void* d_out, int out_size, void* d_ws, size_t ws_size,
                              hipStream_t stream)
{
    const float* feats0 = (const float*)d_in[0];
    const float* feats1 = (const float*)d_in[1];
    const float* t0_pw = (const float*)d_in[2];
    const float* t0_pb = (const float*)d_in[3];
    const float* t0_w2 = (const float*)d_in[4];
    const float* t0_b2 = (const float*)d_in[5];
    const float* t0_g  = (const float*)d_in[6];
    const float* t0_be = (const float*)d_in[7];
    const float* t1_pw = (const float*)d_in[8];
    const float* t1_pb = (const float*)d_in[9];
    const float* t1_w2 = (const float*)d_in[10];
    const float* t1_b2 = (const float*)d_in[11];
    const float* t1_g  = (const float*)d_in[12];
    const float* t1_be = (const float*)d_in[13];
    const float* r_vec = (const float*)d_in[14];
    const float* attn_user = (const float*)d_in[15];
    const float* attn_item = (const float*)d_in[16];
    const float* su_w1 = (const float*)d_in[17];
    const float* su_b1 = (const float*)d_in[18];
    const float* su_w2 = (const float*)d_in[19];
    const float* si_w1 = (const float*)d_in[20];
    const float* si_b1 = (const float*)d_in[21];
    const float* si_w2 = (const float*)d_in[22];
    const float* cw1 = (const float*)d_in[23];
    const float* cb1 = (const float*)d_in[24];
    const float* cw2 = (const float*)d_in[25];
    const int* idx0 = (const int*)d_in[26];
    const int* idx1 = (const int*)d_in[27];
    const int* emi_user = (const int*)d_in[28];
    const int* tgt_user = (const int*)d_in[29];
    const int* emi_item = (const int*)d_in[30];
    const int* tgt_item = (const int*)d_in[31];
    float* outp = (float*)d_out;

    // workspace layout (256B aligned)
    char* ws = (char*)d_ws;
    __hip_bfloat16* feat = (__hip_bfloat16*)(ws + 0);   // 5,120,000
    int*     cnt    = (int*)(ws + 5120000);             // 131,072
    int*     cur    = (int*)(ws + 5251072);             // 131,072 (contiguous with cnt for one memset)
    int*     cur32  = (int*)(ws + 5382144);             // 512
    int*     offs   = (int*)(ws + 5382656);             // 131,088 -> pad 131,328
    float*   s_acc  = (float*)(ws + 5513984);           // 256
    ushort4* binbuf = (ushort4*)(ws + 5514240);         // 6,400,000
    ushort4* nodes  = (ushort4*)(ws + 11914240);        // 6,400,000
    float*   ret_buf= (float*)(ws + 18314240);          // 8,388,608
    __bf16*  wprep  = (__bf16*)(ws + 26702848);         // 262,144  (end ~27.0 MB)
    // w2prep (32KB) aliases the start of `nodes`: written by prep_hist, read by tower
    // (tower_binA), then overwritten by binB which runs strictly after. binA writes
    // only binbuf, so the concurrent tower reads are race-free.
    __bf16*  w2prep = (__bf16*)(ws + 11914240);

    hipMemsetAsync(cnt, 0, 2 * 4 * BBB * sizeof(int), stream);

    prep_hist<<<16 + 4 * ((EEE + 255) / 256), 256, 0, stream>>>(
        t0_pw, t1_pw, t0_w2, t1_w2, wprep, w2prep, tgt_user, tgt_item, cnt);

    scan_kernel<<<4, 256, 0, stream>>>(cnt, offs, cur32, s_acc);

    tower_binA<<<2500 + 4 * ((EEE + CHUNKF - 1) / CHUNKF), 64, 0, stream>>>(
        feats0, feats1, wprep, w2prep, t0_pb, t1_pb,
        t0_b2, t1_b2, t0_g, t1_g, t0_be, t1_be, idx0, idx1, feat,
        tgt_user, tgt_item, emi_user, emi_item, cur32, binbuf);

    binB_kernel<<<dim3(64, 4), 256, 0, stream>>>(offs, cur, binbuf, nodes);

    flash_mp<<<dim3(BBB / 4, 4), 256, 0, stream>>>(feat, nodes, offs, r_vec,
                                                   attn_user, attn_item, ret_buf);

    sem_kernel<<<dim3(BBB / 64, 4), 256, 0, stream>>>(ret_buf, su_w1, su_b1, su_w2,
                                                      si_w1, si_b1, si_w2, s_acc);
    final_kernel<<<BBB / 64, 256, 0, stream>>>(ret_buf, s_acc, cw1, cb1, cw2, outp);
}

// Round 4
// 332.430 us; speedup vs baseline: 1.2749x; 1.0004x over previous
//
#include <hip/hip_runtime.h>
#include <hip/hip_bf16.h>
#include <math.h>

// MAGNN link prediction forward — fp32 compute; feat table stored bf16.
// Tower: barrier-free per-wave MFMA GEMM (split-bf16 hi/lo, 3 MFMAs ~ fp32 accuracy),
//        deep static prefetch (x: 3 K-steps, B: 2 K-steps) to hide L3/L2 latency.
// Flash: deferred-rotation packed-f32 online softmax.
#define NN0 20000
#define NN1 20000
#define NTOT 40000
#define FF0 512
#define HIDD 64
#define EEE 200000
#define BBB 8192
#define AVV 128
#define CHH 128

typedef __bf16 bf16x8 __attribute__((ext_vector_type(8)));
typedef __bf16 bf16x4 __attribute__((ext_vector_type(4)));
typedef float f32x4 __attribute__((ext_vector_type(4)));
typedef float f32x2 __attribute__((ext_vector_type(2)));

__device__ __forceinline__ float fast_tanh(float x) {
    float e2 = __expf(2.f * x);
    return 1.f - 2.f / (e2 + 1.f);
}

__device__ __forceinline__ f32x2 bf2_to_f32x2(unsigned int c) {
    f32x2 r;
    r.x = __uint_as_float(c << 16);
    r.y = __uint_as_float(c & 0xffff0000u);
    return r;
}

// ---------------- fused: weight prep (blocks 0..15) + target histogram (rest) ----------------
// prep: hi/lo bf16 split into exact B-fragment order.
// GEMM1 (pw [512][64]): fragment element (ks, nt, lane, j) holds w[k][n] with
//   k = ks*32 + (lane>>4)*8 + j, n = nt*16 + (lane&15).
// hi at [((ks*4+nt)*64 + lane)*8 + j], lo at +32768 (per tower: 65536 bf16 = 128KB).
// GEMM2 (w2 [64][64]): same formula, ks in 0..1; per tower 8192 bf16 = 16KB.
__global__ __launch_bounds__(256) void prep_hist(
    const float* __restrict__ pw0, const float* __restrict__ pw1,
    const float* __restrict__ w20, const float* __restrict__ w21,
    __bf16* __restrict__ wprep, __bf16* __restrict__ w2prep,
    const int* __restrict__ tgt_user, const int* __restrict__ tgt_item,
    int* __restrict__ cnt)
{
    int bx = blockIdx.x;
    if (bx < 16) {
        int tw = bx & 1, seg = bx >> 1;
        const float* w = tw ? pw1 : pw0;
        __bf16* base = wprep + tw * 65536;
        for (int idx = seg * 4096 + threadIdx.x; idx < (seg + 1) * 4096; idx += 256) {
            int k = idx >> 6, n = idx & 63;
            float v = w[idx];
            __bf16 hi = (__bf16)v;
            __bf16 lo = (__bf16)(v - (float)hi);
            int ks = k >> 5, kb = (k >> 3) & 3, j = k & 7;
            int nt = n >> 4, fr = n & 15;
            int lane = kb * 16 + fr;
            int off = ((ks * 4 + nt) * 64 + lane) * 8 + j;
            base[off] = hi;
            base[32768 + off] = lo;
        }
        const float* w2 = tw ? w21 : w20;
        __bf16* base2 = w2prep + tw * 8192;
        for (int idx = seg * 512 + threadIdx.x; idx < (seg + 1) * 512; idx += 256) {
            int k = idx >> 6, n = idx & 63;
            float v = w2[idx];
            __bf16 hi = (__bf16)v;
            __bf16 lo = (__bf16)(v - (float)hi);
            int ks = k >> 5, kb = (k >> 3) & 3, j = k & 7;
            int nt = n >> 4, fr = n & 15;
            int lane = kb * 16 + fr;
            int off = ((ks * 4 + nt) * 64 + lane) * 8 + j;
            base2[off] = hi;
            base2[4096 + off] = lo;
        }
    } else {
        int flat = bx - 16;                    // 0..3127
        int combo = flat & 3, blk = flat >> 2; // blk 0..781
        const int* tgt = (combo < 2 ? tgt_user : tgt_item) + (long)(combo & 1) * EEE;
        int i = blk * 256 + threadIdx.x;
        if (i < EEE) atomicAdd(&cnt[combo * BBB + tgt[i]], 1);
    }
}

// ---------------- scan: per-combo exclusive prefix over 8192 counters ----------------
__global__ __launch_bounds__(256) void scan_kernel(const int* __restrict__ cnt, int* __restrict__ offs,
                                                   int* __restrict__ cur32, float* __restrict__ s_acc)
{
    int pth = blockIdx.x;
    if (pth == 0 && threadIdx.x < 4) s_acc[threadIdx.x] = 0.f;
    const int* c = cnt + pth * BBB;
    int* o = offs + pth * (BBB + 1);
    __shared__ int part[256];
    int tid = threadIdx.x;
    int base = tid * 32;
    int local[32];
    int sum = 0;
    for (int j = 0; j < 32; j++) { local[j] = sum; sum += c[base + j]; }
    part[tid] = sum;
    __syncthreads();
    for (int d = 1; d < 256; d <<= 1) {
        int v = (tid >= d) ? part[tid - d] : 0;
        __syncthreads();
        part[tid] += v;
        __syncthreads();
    }
    int pre = (tid == 0) ? 0 : part[tid - 1];
    for (int j = 0; j < 32; j++) {
        int val = pre + local[j];
        o[base + j] = val;
        if (((base + j) & 255) == 0) cur32[pth * 32 + ((base + j) >> 8)] = val;
    }
    if (tid == 255) o[BBB] = pre + sum;
}

// ---------------- fused: tower MFMA (blocks 0..2499) + binA coarse binning (rest) ----------------
// Tower: 1 wave per block; wave owns 16 rows x 64 cols, full K=512.
// A fragments direct from global fp32 x (convert in-register, hi/lo split), prefetch dist 3 (L3).
// B fragments direct from prepacked global image (L2-resident), prefetch dist 2. No barriers.
// binA: 64-thread variant, 512 entries/block, LDS-sorted coarse bucket scatter.
#define CHUNKF 512
__global__ __launch_bounds__(64, 3) void tower_binA(
    const float* __restrict__ x0, const float* __restrict__ x1,
    const __bf16* __restrict__ wprep, const __bf16* __restrict__ w2prep,
    const float* __restrict__ pb0, const float* __restrict__ pb1,
    const float* __restrict__ b20, const float* __restrict__ b21,
    const float* __restrict__ g0, const float* __restrict__ g1,
    const float* __restrict__ be0, const float* __restrict__ be1,
    const int* __restrict__ idxa, const int* __restrict__ idxb,
    __hip_bfloat16* __restrict__ feat,
    const int* __restrict__ tgt_user, const int* __restrict__ tgt_item,
    const int* __restrict__ emi_user, const int* __restrict__ emi_item,
    int* __restrict__ cur32, ushort4* __restrict__ binbuf)
{
    __shared__ __align__(16) char pool[4624];
    int bx = blockIdx.x;
    if (bx < 2500) {
        int tile = bx >> 1, tw = bx & 1;
        const float* x  = tw ? x1 : x0;
        const float* pb = tw ? pb1 : pb0;
        const float* b2 = tw ? b21 : b20;
        const float* g  = tw ? g1 : g0;
        const float* be = tw ? be1 : be0;
        const int* idx  = tw ? idxb : idxa;
        float (*hs)[68] = (float(*)[68])pool;

        int l = threadIdx.x;
        int fr = l & 15, kb = l >> 4;
        int row0 = tile * 16;
        const float* xp = x + (long)(row0 + fr) * FF0 + kb * 8;
        const __bf16* bp = wprep + tw * 65536;

        f32x4 acc[4];
#pragma unroll
        for (int nt = 0; nt < 4; nt++) acc[nt] = (f32x4){0.f, 0.f, 0.f, 0.f};

        // deep static prefetch: full unroll keeps all slot indices compile-time (no scratch).
        float4 xA[16], xB[16];
        bf16x8 Bh[16][4], Bl[16][4];

        // prologue: x 3 deep, B 2 deep
#pragma unroll
        for (int k = 0; k < 3; k++) {
            xA[k] = *(const float4*)(xp + k * 32);
            xB[k] = *(const float4*)(xp + k * 32 + 4);
        }
#pragma unroll
        for (int k = 0; k < 2; k++)
#pragma unroll
            for (int nt = 0; nt < 4; nt++) {
                Bh[k][nt] = *(const bf16x8*)(bp + ((k * 4 + nt) * 64 + l) * 8);
                Bl[k][nt] = *(const bf16x8*)(bp + 32768 + ((k * 4 + nt) * 64 + l) * 8);
            }

#pragma unroll
        for (int ks = 0; ks < 16; ks++) {
            if (ks + 3 < 16) {
                xA[ks + 3] = *(const float4*)(xp + (ks + 3) * 32);
                xB[ks + 3] = *(const float4*)(xp + (ks + 3) * 32 + 4);
            }
            if (ks + 2 < 16) {
#pragma unroll
                for (int nt = 0; nt < 4; nt++) {
                    Bh[ks + 2][nt] = *(const bf16x8*)(bp + (((ks + 2) * 4 + nt) * 64 + l) * 8);
                    Bl[ks + 2][nt] = *(const bf16x8*)(bp + 32768 + (((ks + 2) * 4 + nt) * 64 + l) * 8);
                }
            }
            float av[8] = {xA[ks].x, xA[ks].y, xA[ks].z, xA[ks].w,
                           xB[ks].x, xB[ks].y, xB[ks].z, xB[ks].w};
            bf16x8 ah, al;
#pragma unroll
            for (int j = 0; j < 8; j++) {
                __bf16 h = (__bf16)av[j];
                ah[j] = h;
                al[j] = (__bf16)(av[j] - (float)h);
            }
#pragma unroll
            for (int nt = 0; nt < 4; nt++) {
                acc[nt] = __builtin_amdgcn_mfma_f32_16x16x32_bf16(ah, Bh[ks][nt], acc[nt], 0, 0, 0);
                acc[nt] = __builtin_amdgcn_mfma_f32_16x16x32_bf16(al, Bh[ks][nt], acc[nt], 0, 0, 0);
                acc[nt] = __builtin_amdgcn_mfma_f32_16x16x32_bf16(ah, Bl[ks][nt], acc[nt], 0, 0, 0);
            }
        }

        // epilogue 1: z = acc + pb; h = gelu(z) -> hs; acc2 = z + b2
        float pbv[4], b2v[4];
#pragma unroll
        for (int nt = 0; nt < 4; nt++) { pbv[nt] = pb[nt * 16 + fr]; b2v[nt] = b2[nt * 16 + fr]; }
        f32x4 acc2[4];
#pragma unroll
        for (int nt = 0; nt < 4; nt++) {
#pragma unroll
            for (int j = 0; j < 4; j++) {
                float z = acc[nt][j] + pbv[nt];
                float h = 0.5f * z * (1.f + erff(z * 0.70710678118654752f));
                hs[kb * 4 + j][nt * 16 + fr] = h;
                acc2[nt][j] = z + b2v[nt];
            }
        }
        __syncthreads();

        // GEMM2 (MFMA): y = h@w2 + b2 + z
        const __bf16* w2p = w2prep + tw * 8192;
#pragma unroll
        for (int ks = 0; ks < 2; ks++) {
            float4 h0 = *(const float4*)&hs[fr][ks * 32 + kb * 8];
            float4 h1 = *(const float4*)&hs[fr][ks * 32 + kb * 8 + 4];
            float hv[8] = {h0.x, h0.y, h0.z, h0.w, h1.x, h1.y, h1.z, h1.w};
            bf16x8 ah, al;
#pragma unroll
            for (int j = 0; j < 8; j++) {
                __bf16 h = (__bf16)hv[j];
                ah[j] = h;
                al[j] = (__bf16)(hv[j] - (float)h);
            }
#pragma unroll
            for (int nt = 0; nt < 4; nt++) {
                bf16x8 bh2 = *(const bf16x8*)(w2p + ((ks * 4 + nt) * 64 + l) * 8);
                bf16x8 bl2 = *(const bf16x8*)(w2p + 4096 + ((ks * 4 + nt) * 64 + l) * 8);
                acc2[nt] = __builtin_amdgcn_mfma_f32_16x16x32_bf16(ah, bh2, acc2[nt], 0, 0, 0);
                acc2[nt] = __builtin_amdgcn_mfma_f32_16x16x32_bf16(al, bh2, acc2[nt], 0, 0, 0);
                acc2[nt] = __builtin_amdgcn_mfma_f32_16x16x32_bf16(ah, bl2, acc2[nt], 0, 0, 0);
            }
        }
        __syncthreads();

        // LayerNorm in-register
        float gv[4], bev[4];
#pragma unroll
        for (int nt = 0; nt < 4; nt++) { gv[nt] = g[nt * 16 + fr]; bev[nt] = be[nt * 16 + fr]; }
#pragma unroll
        for (int j = 0; j < 4; j++) {
            float p = acc2[0][j] + acc2[1][j] + acc2[2][j] + acc2[3][j];
            p += __shfl_xor(p, 1); p += __shfl_xor(p, 2);
            p += __shfl_xor(p, 4); p += __shfl_xor(p, 8);
            float mu = p * (1.f / 64.f);
            float d[4], vs = 0.f;
#pragma unroll
            for (int nt = 0; nt < 4; nt++) { d[nt] = acc2[nt][j] - mu; vs += d[nt] * d[nt]; }
            vs += __shfl_xor(vs, 1); vs += __shfl_xor(vs, 2);
            vs += __shfl_xor(vs, 4); vs += __shfl_xor(vs, 8);
            float is = 1.f / sqrtf(vs * (1.f / 64.f) + 1e-5f);
#pragma unroll
            for (int nt = 0; nt < 4; nt++)
                hs[kb * 4 + j][nt * 16 + fr] = d[nt] * is * gv[nt] + bev[nt];
        }
        __syncthreads();
#pragma unroll 4
        for (int r = 0; r < 16; r++) {
            int grow = row0 + r;
            feat[(long)idx[grow] * HIDD + l] = __float2bfloat16(hs[r][l]);
        }
    } else {
        int flat = bx - 2500;
        int combo = flat & 3;
        int base = (flat >> 2) * CHUNKF;
        const int* tgt = (combo < 2 ? tgt_user : tgt_item) + (long)(combo & 1) * EEE;
        const int* emi = (combo < 2 ? emi_user : emi_item) + (long)(combo & 1) * EEE * 3;
        ushort4* sbuf = (ushort4*)pool;
        int* lcnt  = (int*)(pool + 4096);
        int* lofs  = lcnt + 32;
        int* gbase = lofs + 33;
        int* lcur  = gbase + 32;
        int tid = threadIdx.x;
        if (tid < 32) { lcnt[tid] = 0; lcur[tid] = 0; }
        __syncthreads();
        ushort4 ent[8]; int bk[8];
#pragma unroll
        for (int ps = 0; ps < 8; ps++) {
            int i = base + ps * 64 + tid;
            if (i < EEE) {
                int t = tgt[i];
                ent[ps] = make_ushort4((unsigned short)emi[3 * i], (unsigned short)emi[3 * i + 1],
                                       (unsigned short)emi[3 * i + 2], (unsigned short)t);
                bk[ps] = t >> 8;
                atomicAdd(&lcnt[bk[ps]], 1);
            } else bk[ps] = -1;
        }
        __syncthreads();
        if (tid == 0) {
            int run = 0;
            for (int k = 0; k < 32; k++) { lofs[k] = run; run += lcnt[k]; }
            lofs[32] = run;
        }
        __syncthreads();
        if (tid < 32) gbase[tid] = atomicAdd(&cur32[combo * 32 + tid], lcnt[tid]);
        __syncthreads();
#pragma unroll
        for (int ps = 0; ps < 8; ps++) {
            if (bk[ps] >= 0) {
                int pos = lofs[bk[ps]] + atomicAdd(&lcur[bk[ps]], 1);
                sbuf[pos] = ent[ps];
            }
        }
        __syncthreads();
        int total = lofs[32];
        ushort4* dst = binbuf + (long)combo * EEE;
        for (int j = tid; j < total; j += 64) {
            ushort4 e = sbuf[j];
            int k = e.w >> 8;
            dst[gbase[k] + (j - lofs[k])] = e;
        }
    }
}

// pass B: within each coarse bucket (contiguous ~50KB window), place entries at exact CSR position
__global__ __launch_bounds__(256) void binB_kernel(
    const int* __restrict__ offs, int* __restrict__ cur,
    const ushort4* __restrict__ binbuf, ushort4* __restrict__ nodes)
{
    int combo = blockIdx.y;
    int k = blockIdx.x >> 1, part = blockIdx.x & 1;
    const int* of = offs + combo * (BBB + 1);
    int rbeg = of[k << 8], rend = of[(k + 1) << 8];
    const ushort4* src = binbuf + (long)combo * EEE;
    ushort4* dst = nodes + (long)combo * EEE;
    int* cu = cur + combo * BBB;
    for (int j = rbeg + part * 256 + threadIdx.x; j < rend; j += 512) {
        ushort4 e = src[j];
        int t = e.w;
        int pos = of[t] + atomicAdd(&cu[t], 1);
        dst[pos] = e;
    }
}

// ---------------- flash metapath: deferred rotation + packed f32 + online softmax + ELU ----------------
// hidden = (u0 + u2 + R*u1)/3. Rotation is linear -> accumulate A02=Σw(u0+u2), A1=Σw*u1,
// apply R once at the end. Logit folds R into attn: e = (u0+u2)·(a/3) + u1·(Rᵀa/3).
__global__ __launch_bounds__(256) void flash_mp(
    const __hip_bfloat16* __restrict__ feat, const ushort4* __restrict__ nodes,
    const int* __restrict__ offs, const float* __restrict__ r_vec,
    const float* __restrict__ attn_user, const float* __restrict__ attn_item,
    float* __restrict__ ret)
{
    int combo = blockIdx.y;
    int wid = threadIdx.x >> 6, lane = threadIdx.x & 63;
    int half = lane >> 5, p = lane & 31;
    int side = combo >> 1;
    const float* attn = (side == 0 ? attn_user : attn_item) + (combo & 1) * 64;
    const unsigned int* f2 = (const unsigned int*)feat;
    float2 rb = ((const float2*)r_vec)[p];
    float invn = 1.f / sqrtf(rb.x * rb.x + rb.y * rb.y);
    float rvx = rb.x * invn, rvy = rb.y * invn;
    if (side == 0) rvy = -rvy;
    float aRe = attn[2 * p], aIm = attn[2 * p + 1];
    f32x2 av  = { aRe * (1.f / 3.f), aIm * (1.f / 3.f) };
    f32x2 apv = { (rvx * aRe + rvy * aIm) * (1.f / 3.f),
                  (rvx * aIm - rvy * aRe) * (1.f / 3.f) };
    int t = blockIdx.x * 4 + wid;
    const int* of = offs + combo * (BBB + 1);
    int beg = of[t], end = of[t + 1];
    int n = end - beg;
    const ushort4* nd = nodes + (long)combo * EEE;

    float m = -3.4e38f, s = 0.f;
    f32x2 A02 = {0.f, 0.f}, A1 = {0.f, 0.f};

    unsigned int c0[4], c1[4], c2[4];
    ushort4 nq[4];
    if (n > 0) {
#pragma unroll
        for (int q = 0; q < 4; q++) {
            ushort4 a = nd[min(beg + 2 * q + half, EEE - 1)];
            c0[q] = f2[(int)a.x * 32 + p];
            c1[q] = f2[(int)a.y * 32 + p];
            c2[q] = f2[(int)a.z * 32 + p];
        }
#pragma unroll
        for (int q = 0; q < 4; q++)
            nq[q] = nd[min(beg + 8 + 2 * q + half, EEE - 1)];
    }
    for (int it = 0; it < n; it += 8) {
        f32x2 u1[4], v02[4];
        float e[4];
#pragma unroll
        for (int q = 0; q < 4; q++) {
            f32x2 u0 = bf2_to_f32x2(c0[q]);
            u1[q]    = bf2_to_f32x2(c1[q]);
            f32x2 u2 = bf2_to_f32x2(c2[q]);
            v02[q] = u0 + u2;
        }
        if (it + 8 < n) {
#pragma unroll
            for (int q = 0; q < 4; q++) {
                c0[q] = f2[(int)nq[q].x * 32 + p];
                c1[q] = f2[(int)nq[q].y * 32 + p];
                c2[q] = f2[(int)nq[q].z * 32 + p];
            }
#pragma unroll
            for (int q = 0; q < 4; q++)
                nq[q] = nd[min(beg + it + 16 + 2 * q + half, EEE - 1)];
        }
#pragma unroll
        for (int q = 0; q < 4; q++) {
            f32x2 tt = v02[q] * av + u1[q] * apv;
            float pa = tt.x + tt.y;
            pa += __shfl_xor(pa, 1);
            pa += __shfl_xor(pa, 2);
            e[q] = fmaxf(pa, 0.01f * pa);        // leaky_relu
        }
        if (it + 8 > n) {                        // tail chunk only (wave-uniform)
#pragma unroll
            for (int q = 0; q < 4; q++)
                if (it + 2 * q + half >= n) e[q] = -3.4e38f;
        }
        float mx = fmaxf(fmaxf(e[0], e[1]), fmaxf(e[2], e[3]));
        float mn = fmaxf(m, fmaxf(mx, __shfl_xor(mx, 32)));
        float alpha = __expf(m - mn);
        s *= alpha; A02 *= alpha; A1 *= alpha;
        float wl = 0.f;
#pragma unroll
        for (int q = 0; q < 4; q++) {
            float w = __expf(e[q] - mn);
            wl += w;
            A02 += v02[q] * w;
            A1  += u1[q] * w;
        }
        s += wl + __shfl_xor(wl, 32);
        m = mn;
    }
    float Sx = A02.x + __shfl_xor(A02.x, 32);
    float Sy = A02.y + __shfl_xor(A02.y, 32);
    float Tx = A1.x + __shfl_xor(A1.x, 32);
    float Ty = A1.y + __shfl_xor(A1.y, 32);
    float inv = (1.f / 3.f) / (s + 1e-9f);
    float vx = (Sx + rvx * Tx - rvy * Ty) * inv;
    float vy = (Sy + rvx * Ty + rvy * Tx) * inv;
    vx = vx > 0.f ? vx : __expf(vx) - 1.f;       // ELU
    vy = vy > 0.f ? vy : __expf(vy) - 1.f;
    if (half == 0)
        ((float2*)ret)[((long)combo * BBB + t) * 32 + p] = make_float2(vx, vy);
}

// ---------------- semantic score GEMM: s_acc[combo] = sum_b tanh(ret_b @ w1 + b1) @ w2 ----------------
__global__ __launch_bounds__(256) void sem_kernel(
    const float* __restrict__ ret,
    const float* __restrict__ su_w1, const float* __restrict__ su_b1, const float* __restrict__ su_w2,
    const float* __restrict__ si_w1, const float* __restrict__ si_b1, const float* __restrict__ si_w2,
    float* __restrict__ s_acc)
{
    int combo = blockIdx.y;
    int side = combo >> 1;
    const float* w1 = side ? si_w1 : su_w1;
    const float* b1 = side ? si_b1 : su_b1;
    const float* w2 = side ? si_w2 : su_w2;
    __shared__ float vs[64][68];
    __shared__ float w1s[64][128];
    int tid = threadIdx.x;
    int rowbase = blockIdx.x * 64;
    const float4* r4 = (const float4*)ret;
    for (int li = tid; li < 1024; li += 256) {
        int r = li >> 4, c4 = li & 15;
        float4 v = r4[((long)combo * BBB + rowbase + r) * 16 + c4];
        *(float4*)&vs[r][c4 * 4] = v;
    }
    const float4* w14 = (const float4*)w1;
    for (int li = tid; li < 2048; li += 256) {
        float4 v = w14[li];
        *(float4*)&w1s[li >> 5][(li & 31) * 4] = v;
    }
    __syncthreads();
    int ct = tid & 15, rt = tid >> 4;
    float acc[4][8];
#pragma unroll
    for (int cc = 0; cc < 8; cc++) {
        float b = b1[8 * ct + cc];
#pragma unroll
        for (int j = 0; j < 4; j++) acc[j][cc] = b;
    }
    for (int k = 0; k < 64; k += 4) {
        float4 xv[4];
#pragma unroll
        for (int j = 0; j < 4; j++) xv[j] = *(const float4*)&vs[4 * rt + j][k];
#pragma unroll
        for (int kk = 0; kk < 4; kk++) {
            float4 wv0 = *(const float4*)&w1s[k + kk][8 * ct];
            float4 wv1 = *(const float4*)&w1s[k + kk][8 * ct + 4];
#pragma unroll
            for (int j = 0; j < 4; j++) {
                float xx = kk == 0 ? xv[j].x : kk == 1 ? xv[j].y : kk == 2 ? xv[j].z : xv[j].w;
                acc[j][0] = fmaf(xx, wv0.x, acc[j][0]);
                acc[j][1] = fmaf(xx, wv0.y, acc[j][1]);
                acc[j][2] = fmaf(xx, wv0.z, acc[j][2]);
                acc[j][3] = fmaf(xx, wv0.w, acc[j][3]);
                acc[j][4] = fmaf(xx, wv1.x, acc[j][4]);
                acc[j][5] = fmaf(xx, wv1.y, acc[j][5]);
                acc[j][6] = fmaf(xx, wv1.z, acc[j][6]);
                acc[j][7] = fmaf(xx, wv1.w, acc[j][7]);
            }
        }
    }
    float tot = 0.f;
#pragma unroll
    for (int cc = 0; cc < 8; cc++) {
        float w2v = w2[8 * ct + cc];
#pragma unroll
        for (int j = 0; j < 4; j++) tot += fast_tanh(acc[j][cc]) * w2v;
    }
    for (int off = 32; off; off >>= 1) tot += __shfl_xor(tot, off);
    __shared__ float red[4];
    int lane = tid & 63, wid = tid >> 6;
    if (lane == 0) red[wid] = tot;
    __syncthreads();
    if (tid == 0) atomicAdd(&s_acc[combo], red[0] + red[1] + red[2] + red[3]);
}

// ---------------- final product MLP + softmax (beta inline, GEMM-tiled) ----------------
__global__ __launch_bounds__(256) void final_kernel(
    const float* __restrict__ ret, const float* __restrict__ s_acc,
    const float* __restrict__ cw1, const float* __restrict__ cb1, const float* __restrict__ cw2,
    float* __restrict__ outp)
{
    float s0 = s_acc[0] * (1.f / BBB), s1 = s_acc[1] * (1.f / BBB);
    float s2 = s_acc[2] * (1.f / BBB), s3 = s_acc[3] * (1.f / BBB);
    float mu = fmaxf(s0, s1);
    float e0 = __expf(s0 - mu), e1 = __expf(s1 - mu);
    float bu0 = e0 / (e0 + e1), bu1 = e1 / (e0 + e1);
    float mi = fmaxf(s2, s3);
    float f0 = __expf(s2 - mi), f1 = __expf(s3 - mi);
    float bi0 = f0 / (f0 + f1), bi1 = f1 / (f0 + f1);

    __shared__ float xsld[64][68];
    __shared__ float w1s[64][128];
    int tid = threadIdx.x;
    int rowbase = blockIdx.x * 64;
    const float4* r4 = (const float4*)ret;
    for (int li = tid; li < 1024; li += 256) {
        int r = li >> 4, c4 = li & 15;
        float4 a = r4[((long)0 * BBB + rowbase + r) * 16 + c4];
        float4 b = r4[((long)1 * BBB + rowbase + r) * 16 + c4];
        float4 cc = r4[((long)2 * BBB + rowbase + r) * 16 + c4];
        float4 d = r4[((long)3 * BBB + rowbase + r) * 16 + c4];
        float4 xv;
        xv.x = (bu0 * a.x + bu1 * b.x) * (bi0 * cc.x + bi1 * d.x);
        xv.y = (bu0 * a.y + bu1 * b.y) * (bi0 * cc.y + bi1 * d.y);
        xv.z = (bu0 * a.z + bu1 * b.z) * (bi0 * cc.z + bi1 * d.z);
        xv.w = (bu0 * a.w + bu1 * b.w) * (bi0 * cc.w + bi1 * d.w);
        *(float4*)&xsld[r][c4 * 4] = xv;
    }
    const float4* w14 = (const float4*)cw1;
    for (int li = tid; li < 2048; li += 256) {
        float4 v = w14[li];
        *(float4*)&w1s[li >> 5][(li & 31) * 4] = v;
    }
    __syncthreads();
    int ct = tid & 15, rt = tid >> 4;
    float acc[4][8];
#pragma unroll
    for (int cc = 0; cc < 8; cc++) {
        float b = cb1[8 * ct + cc];
#pragma unroll
        for (int j = 0; j < 4; j++) acc[j][cc] = b;
    }
    for (int k = 0; k < 64; k += 4) {
        float4 xv[4];
#pragma unroll
        for (int j = 0; j < 4; j++) xv[j] = *(const float4*)&xsld[4 * rt + j][k];
#pragma unroll
        for (int kk = 0; kk < 4; kk++) {
            float4 wv0 = *(const float4*)&w1s[k + kk][8 * ct];
            float4 wv1 = *(const float4*)&w1s[k + kk][8 * ct + 4];
#pragma unroll
            for (int j = 0; j < 4; j++) {
                float xx = kk == 0 ? xv[j].x : kk == 1 ? xv[j].y : kk == 2 ? xv[j].z : xv[j].w;
                acc[j][0] = fmaf(xx, wv0.x, acc[j][0]);
                acc[j][1] = fmaf(xx, wv0.y, acc[j][1]);
                acc[j][2] = fmaf(xx, wv0.z, acc[j][2]);
                acc[j][3] = fmaf(xx, wv0.w, acc[j][3]);
                acc[j][4] = fmaf(xx, wv1.x, acc[j][4]);
                acc[j][5] = fmaf(xx, wv1.y, acc[j][5]);
                acc[j][6] = fmaf(xx, wv1.z, acc[j][6]);
                acc[j][7] = fmaf(xx, wv1.w, acc[j][7]);
            }
        }
    }
    float pp0[4], pp1[4];
#pragma unroll
    for (int j = 0; j < 4; j++) { pp0[j] = 0.f; pp1[j] = 0.f; }
#pragma unroll
    for (int cc = 0; cc < 8; cc++) {
        int col = 8 * ct + cc;
        float c0 = cw2[col * 2], c1 = cw2[col * 2 + 1];
#pragma unroll
        for (int j = 0; j < 4; j++) {
            float h = fmaxf(acc[j][cc], 0.f);
            pp0[j] = fmaf(h, c0, pp0[j]);
            pp1[j] = fmaf(h, c1, pp1[j]);
        }
    }
    __syncthreads();
    float2* red = (float2*)xsld;
#pragma unroll
    for (int j = 0; j < 4; j++)
        red[(4 * rt + j) * 16 + ct] = make_float2(pp0[j], pp1[j]);
    __syncthreads();
    if (tid < 64) {
        float q0 = 0.f, q1 = 0.f;
        for (int i = 0; i < 16; i++) {
            float2 e = red[tid * 16 + i];
            q0 += e.x; q1 += e.y;
        }
        float mx = fmaxf(q0, q1);
        float a0 = __expf(q0 - mx), a1 = __expf(q1 - mx);
        float dn = a0 + a1;
        outp[(rowbase + tid) * 2] = a0 / dn;
        outp[(rowbase + tid) * 2 + 1] = a1 / dn;
    }
}

extern "C" void kernel_launch(void* const* d_in, const int* in_sizes, int n_in,
                              void* d_out, int out_size, void* d_ws, size_t ws_size,
                              hipStream_t stream)
{
    const float* feats0 = (const float*)d_in[0];
    const float* feats1 = (const float*)d_in[1];
    const float* t0_pw = (const float*)d_in[2];
    const float* t0_pb = (const float*)d_in[3];
    const float* t0_w2 = (const float*)d_in[4];
    const float* t0_b2 = (const float*)d_in[5];
    const float* t0_g  = (const float*)d_in[6];
    const float* t0_be = (const float*)d_in[7];
    const float* t1_pw = (const float*)d_in[8];
    const float* t1_pb = (const float*)d_in[9];
    const float* t1_w2 = (const float*)d_in[10];
    const float* t1_b2 = (const float*)d_in[11];
    const float* t1_g  = (const float*)d_in[12];
    const float* t1_be = (const float*)d_in[13];
    const float* r_vec = (const float*)d_in[14];
    const float* attn_user = (const float*)d_in[15];
    const float* attn_item = (const float*)d_in[16];
    const float* su_w1 = (const float*)d_in[17];
    const float* su_b1 = (const float*)d_in[18];
    const float* su_w2 = (const float*)d_in[19];
    const float* si_w1 = (const float*)d_in[20];
    const float* si_b1 = (const float*)d_in[21];
    const float* si_w2 = (const float*)d_in[22];
    const float* cw1 = (const float*)d_in[23];
    const float* cb1 = (const float*)d_in[24];
    const float* cw2 = (const float*)d_in[25];
    const int* idx0 = (const int*)d_in[26];
    const int* idx1 = (const int*)d_in[27];
    const int* emi_user = (const int*)d_in[28];
    const int* tgt_user = (const int*)d_in[29];
    const int* emi_item = (const int*)d_in[30];
    const int* tgt_item = (const int*)d_in[31];
    float* outp = (float*)d_out;

    // workspace layout (256B aligned)
    char* ws = (char*)d_ws;
    __hip_bfloat16* feat = (__hip_bfloat16*)(ws + 0);   // 5,120,000
    int*     cnt    = (int*)(ws + 5120000);             // 131,072
    int*     cur    = (int*)(ws + 5251072);             // 131,072 (contiguous with cnt for one memset)
    int*     cur32  = (int*)(ws + 5382144);             // 512
    int*     offs   = (int*)(ws + 5382656);             // 131,088 -> pad 131,328
    float*   s_acc  = (float*)(ws + 5513984);           // 256
    ushort4* binbuf = (ushort4*)(ws + 5514240);         // 6,400,000
    ushort4* nodes  = (ushort4*)(ws + 11914240);        // 6,400,000
    float*   ret_buf= (float*)(ws + 18314240);          // 8,388,608
    __bf16*  wprep  = (__bf16*)(ws + 26702848);         // 262,144  (end ~27.0 MB)
    // w2prep (32KB) aliases the start of `nodes`: written by prep_hist, read by tower
    // (tower_binA), then overwritten by binB which runs strictly after. binA writes
    // only binbuf, so the concurrent tower reads are race-free.
    __bf16*  w2prep = (__bf16*)(ws + 11914240);

    hipMemsetAsync(cnt, 0, 2 * 4 * BBB * sizeof(int), stream);

    prep_hist<<<16 + 4 * ((EEE + 255) / 256), 256, 0, stream>>>(
        t0_pw, t1_pw, t0_w2, t1_w2, wprep, w2prep, tgt_user, tgt_item, cnt);

    scan_kernel<<<4, 256, 0, stream>>>(cnt, offs, cur32, s_acc);

    tower_binA<<<2500 + 4 * ((EEE + CHUNKF - 1) / CHUNKF), 64, 0, stream>>>(
        feats0, feats1, wprep, w2prep, t0_pb, t1_pb,
        t0_b2, t1_b2, t0_g, t1_g, t0_be, t1_be, idx0, idx1, feat,
        tgt_user, tgt_item, emi_user, emi_item, cur32, binbuf);

    binB_kernel<<<dim3(64, 4), 256, 0, stream>>>(offs, cur, binbuf, nodes);

    flash_mp<<<dim3(BBB / 4, 4), 256, 0, stream>>>(feat, nodes, offs, r_vec,
                                                   attn_user, attn_item, ret_buf);

    sem_kernel<<<dim3(BBB / 64, 4), 256, 0, stream>>>(ret_buf, su_w1, su_b1, su_w2,
                                                      si_w1, si_b1, si_w2, s_acc);
    final_kernel<<<BBB / 64, 256, 0, stream>>>(ret_buf, s_acc, cw1, cb1, cw2, outp);
}